// Round 5
// baseline (1205.161 us; speedup 1.0000x reference)
//
#include <hip/hip_runtime.h>
#include <hip/hip_bf16.h>
#include <math.h>

#define NB 2
#define NN 1024
#define ND 256
#define NL 6
#define NP (NN + 1)

typedef unsigned short u16;
typedef __attribute__((ext_vector_type(8))) short bf16x8;
typedef __attribute__((ext_vector_type(4))) float f32x4;

__device__ __forceinline__ u16 f2b(float f) {
    union { float f; unsigned u; } v; v.f = f;
    unsigned r = v.u + 0x7FFFu + ((v.u >> 16) & 1u);
    return (u16)(r >> 16);
}
__device__ __forceinline__ float b2f(u16 b) {
    union { unsigned u; float f; } v; v.u = ((unsigned)b) << 16;
    return v.f;
}
__device__ __forceinline__ float logsigf(float x) {
    return (x >= 0.f) ? -log1pf(expf(-x)) : (x - log1pf(expf(x)));
}

// ---------------- RoPE tables (both tensors, one launch) ----------------
__global__ void rope_cs_kernel(const float* __restrict__ k0p, const float* __restrict__ k1p,
                               const float* __restrict__ fx, const float* __restrict__ fy,
                               float* __restrict__ cs, float* __restrict__ sn) {
    int idx = blockIdx.x * 256 + threadIdx.x;      // 4096*64
    int row = idx >> 6, j = idx & 63;
    const float* kp = (row < 2048) ? k0p + (size_t)row * 2 : k1p + (size_t)(row - 2048) * 2;
    float kx = kp[0], ky = kp[1];
    float f;
    if (j < 32) f = ((kx - 512.f) * (1.f / 512.f)) * fx[j >> 1];
    else        f = ((ky - 384.f) * (1.f / 512.f)) * fy[(j - 32) >> 1];
    cs[idx] = cosf(f);
    sn[idx] = sinf(f);
}

// ---------------- copy both desc tensors + bf16 mirror, one launch ----------------
__global__ void copyconv_kernel(const float* __restrict__ d0, const float* __restrict__ d1,
                                float* __restrict__ outf, u16* __restrict__ outb) {
    int i = blockIdx.x * 256 + threadIdx.x;        // 2*524288
    float v = (i < 524288) ? d0[i] : d1[i - 524288];
    outf[i] = v; outb[i] = f2b(v);
}

// ------- multi-weight convert+transpose: src [perT][K][N] f32 -> dst [perT(oz)][N][K] bf16 ----
struct WP6 {
    const float* s[6];
    u16* d[6];
    unsigned long long oz[6];
};
__global__ void wconvM_kernel(WP6 w, int perT, int K, int N) {
    __shared__ float t[32][33];
    int z = blockIdx.z;
    int p = z / perT, l = z - p * perT;
    const float* W = w.s[p] + (size_t)l * K * N;
    u16* Wt = w.d[p] + (size_t)l * w.oz[p];
    int k0 = blockIdx.y * 32, n0 = blockIdx.x * 32;
    int tx = threadIdx.x, ty = threadIdx.y;  // 32 x 8
    for (int i = 0; i < 32; i += 8)
        t[ty + i][tx] = W[(size_t)(k0 + ty + i) * N + n0 + tx];
    __syncthreads();
    for (int i = 0; i < 32; i += 8)
        Wt[(size_t)(n0 + ty + i) * K + k0 + tx] = f2b(t[tx][ty + i]);
}

__global__ void biaspack_kernel(const float* __restrict__ b0, const float* __restrict__ b1,
                                float* __restrict__ out, int L) {
    int idx = blockIdx.x * 256 + threadIdx.x;
    if (idx >= L * 512) return;
    int i = idx >> 9, c = idx & 511;
    out[idx] = (c < 256) ? b0[i * 256 + c] : b1[i * 256 + c - 256];
}

// ======= generic GEMM: BK=64, double-buffered LDS, one barrier/iter =======
__global__ __launch_bounds__(256)
void gemm_mfma(const u16* __restrict__ A, const u16* __restrict__ A2,
               const u16* __restrict__ Bt, const float* __restrict__ bias,
               const float* __restrict__ res, float* __restrict__ Cf, u16* __restrict__ Cb,
               int M, int N, int K, float scale_lo, float scale_hi,
               const float* __restrict__ csp, const float* __restrict__ snp) {
    __shared__ u16 As[2][64 * 72];
    __shared__ u16 Bs[2][64 * 72];
    int tid = threadIdx.x;
    int lane = tid & 63, wave = tid >> 6;
    int row0 = blockIdx.y * 64, col0 = blockIdx.x * 64;
    int wm = (wave >> 1) * 32, wn = (wave & 1) * 32;
    int l15 = lane & 15, l4 = lane >> 4;
    f32x4 acc[2][2] = {};
    int srl = tid >> 3, sc8 = (tid & 7) * 8;

    auto loadA = [&](int k0, int it) -> bf16x8 {
        int rr = row0 + srl + it * 32;
        int kg = k0 + sc8;
        const u16* src;
        if (A2) src = (kg < 256) ? &A[(size_t)rr * 256 + kg] : &A2[(size_t)rr * 256 + kg - 256];
        else    src = &A[(size_t)rr * K + kg];
        return *(const bf16x8*)src;
    };
    auto loadB = [&](int k0, int it) -> bf16x8 {
        return *(const bf16x8*)&Bt[(size_t)(col0 + srl + it * 32) * K + k0 + sc8];
    };

    bf16x8 rA0 = loadA(0, 0), rA1 = loadA(0, 1);
    bf16x8 rB0 = loadB(0, 0), rB1 = loadB(0, 1);
    *(bf16x8*)&As[0][srl * 72 + sc8] = rA0;
    *(bf16x8*)&As[0][(srl + 32) * 72 + sc8] = rA1;
    *(bf16x8*)&Bs[0][srl * 72 + sc8] = rB0;
    *(bf16x8*)&Bs[0][(srl + 32) * 72 + sc8] = rB1;
    __syncthreads();

    int nt = K >> 6;
    for (int t = 0; t < nt; ++t) {
        int buf = t & 1;
        bool more = (t + 1) < nt;
        if (more) {
            rA0 = loadA((t + 1) * 64, 0); rA1 = loadA((t + 1) * 64, 1);
            rB0 = loadB((t + 1) * 64, 0); rB1 = loadB((t + 1) * 64, 1);
        }
#pragma unroll
        for (int ks = 0; ks < 2; ++ks) {
            bf16x8 a0 = *(bf16x8*)&As[buf][(wm + l15) * 72 + ks * 32 + l4 * 8];
            bf16x8 a1 = *(bf16x8*)&As[buf][(wm + 16 + l15) * 72 + ks * 32 + l4 * 8];
            bf16x8 b0 = *(bf16x8*)&Bs[buf][(wn + l15) * 72 + ks * 32 + l4 * 8];
            bf16x8 b1 = *(bf16x8*)&Bs[buf][(wn + 16 + l15) * 72 + ks * 32 + l4 * 8];
            acc[0][0] = __builtin_amdgcn_mfma_f32_16x16x32_bf16(a0, b0, acc[0][0], 0, 0, 0);
            acc[0][1] = __builtin_amdgcn_mfma_f32_16x16x32_bf16(a0, b1, acc[0][1], 0, 0, 0);
            acc[1][0] = __builtin_amdgcn_mfma_f32_16x16x32_bf16(a1, b0, acc[1][0], 0, 0, 0);
            acc[1][1] = __builtin_amdgcn_mfma_f32_16x16x32_bf16(a1, b1, acc[1][1], 0, 0, 0);
        }
        if (more) {
            int nb = buf ^ 1;
            *(bf16x8*)&As[nb][srl * 72 + sc8] = rA0;
            *(bf16x8*)&As[nb][(srl + 32) * 72 + sc8] = rA1;
            *(bf16x8*)&Bs[nb][srl * 72 + sc8] = rB0;
            *(bf16x8*)&Bs[nb][(srl + 32) * 72 + sc8] = rB1;
        }
        __syncthreads();
    }
#pragma unroll
    for (int mi = 0; mi < 2; ++mi)
#pragma unroll
        for (int ni = 0; ni < 2; ++ni)
#pragma unroll
            for (int j = 0; j < 4; ++j) {
                int r = row0 + wm + mi * 16 + l4 * 4 + j;
                int c = col0 + wn + ni * 16 + l15;
                float v = acc[mi][ni][j] + (bias ? bias[c] : 0.f);
                float pn = __shfl_xor(v, 1);
                if (csp && c < 256) {
                    float cc = csp[(size_t)r * 64 + (c & 63)];
                    float ss = snp[(size_t)r * 64 + (c & 63)];
                    v = (c & 1) ? (v * cc + pn * ss) : (v * cc - pn * ss);
                }
                v *= (c < 256) ? scale_lo : scale_hi;
                if (res) v += res[(size_t)r * N + c];
                if (Cf) Cf[(size_t)r * N + c] = v;
                if (Cb) Cb[(size_t)r * N + c] = f2b(v);
            }
}

// ======= O-proj GEMM with fused flash-partial combine on A-load =======
// A[r][kg] = (O0[r,kg]*e0 + O1[r,kg]*e1) / (l0*e0+l1*e1), h = kg>>6
__global__ __launch_bounds__(256)
void gemm_oproj(const float* __restrict__ Op, const float* __restrict__ mp,
                const float* __restrict__ lp, const u16* __restrict__ Bt,
                const float* __restrict__ bias, u16* __restrict__ Cb) {
    __shared__ u16 As[2][64 * 72];
    __shared__ u16 Bs[2][64 * 72];
    const int N = 256, K = 256;
    int tid = threadIdx.x;
    int lane = tid & 63, wave = tid >> 6;
    int row0 = blockIdx.y * 64, col0 = blockIdx.x * 64;
    int wm = (wave >> 1) * 32, wn = (wave & 1) * 32;
    int l15 = lane & 15, l4 = lane >> 4;
    f32x4 acc[2][2] = {};
    int srl = tid >> 3, sc8 = (tid & 7) * 8;

    auto loadA = [&](int k0, int it) -> bf16x8 {
        int rg = row0 + srl + it * 32;
        int kg = k0 + sc8;
        int h = kg >> 6, d0 = kg & 63;
        int t = rg >> 11, bb = (rg >> 10) & 1, iq = rg & 1023;
        int y = t * 8 + bb * 4 + h;
        int ri = y * 1024 + iq;
        size_t base0 = (size_t)ri * 64 + d0;
        size_t base1 = base0 + (size_t)16384 * 64;
        f32x4 a0 = *(const f32x4*)&Op[base0];
        f32x4 a1 = *(const f32x4*)&Op[base0 + 4];
        f32x4 c0 = *(const f32x4*)&Op[base1];
        f32x4 c1 = *(const f32x4*)&Op[base1 + 4];
        float m0 = mp[ri], m1 = mp[16384 + ri];
        float l0 = lp[ri], l1 = lp[16384 + ri];
        float mf = fmaxf(m0, m1);
        float e0 = __expf(m0 - mf), e1 = __expf(m1 - mf);
        float inv = 1.f / (l0 * e0 + l1 * e1);
        e0 *= inv; e1 *= inv;
        u16 o[8];
#pragma unroll
        for (int e = 0; e < 4; ++e) {
            o[e] = f2b(a0[e] * e0 + c0[e] * e1);
            o[4 + e] = f2b(a1[e] * e0 + c1[e] * e1);
        }
        return *(bf16x8*)o;
    };
    auto loadB = [&](int k0, int it) -> bf16x8 {
        return *(const bf16x8*)&Bt[(size_t)(col0 + srl + it * 32) * K + k0 + sc8];
    };

    bf16x8 rA0 = loadA(0, 0), rA1 = loadA(0, 1);
    bf16x8 rB0 = loadB(0, 0), rB1 = loadB(0, 1);
    *(bf16x8*)&As[0][srl * 72 + sc8] = rA0;
    *(bf16x8*)&As[0][(srl + 32) * 72 + sc8] = rA1;
    *(bf16x8*)&Bs[0][srl * 72 + sc8] = rB0;
    *(bf16x8*)&Bs[0][(srl + 32) * 72 + sc8] = rB1;
    __syncthreads();

    for (int t = 0; t < 4; ++t) {
        int buf = t & 1;
        bool more = (t + 1) < 4;
        if (more) {
            rA0 = loadA((t + 1) * 64, 0); rA1 = loadA((t + 1) * 64, 1);
            rB0 = loadB((t + 1) * 64, 0); rB1 = loadB((t + 1) * 64, 1);
        }
#pragma unroll
        for (int ks = 0; ks < 2; ++ks) {
            bf16x8 a0 = *(bf16x8*)&As[buf][(wm + l15) * 72 + ks * 32 + l4 * 8];
            bf16x8 a1 = *(bf16x8*)&As[buf][(wm + 16 + l15) * 72 + ks * 32 + l4 * 8];
            bf16x8 b0 = *(bf16x8*)&Bs[buf][(wn + l15) * 72 + ks * 32 + l4 * 8];
            bf16x8 b1 = *(bf16x8*)&Bs[buf][(wn + 16 + l15) * 72 + ks * 32 + l4 * 8];
            acc[0][0] = __builtin_amdgcn_mfma_f32_16x16x32_bf16(a0, b0, acc[0][0], 0, 0, 0);
            acc[0][1] = __builtin_amdgcn_mfma_f32_16x16x32_bf16(a0, b1, acc[0][1], 0, 0, 0);
            acc[1][0] = __builtin_amdgcn_mfma_f32_16x16x32_bf16(a1, b0, acc[1][0], 0, 0, 0);
            acc[1][1] = __builtin_amdgcn_mfma_f32_16x16x32_bf16(a1, b1, acc[1][1], 0, 0, 0);
        }
        if (more) {
            int nb = buf ^ 1;
            *(bf16x8*)&As[nb][srl * 72 + sc8] = rA0;
            *(bf16x8*)&As[nb][(srl + 32) * 72 + sc8] = rA1;
            *(bf16x8*)&Bs[nb][srl * 72 + sc8] = rB0;
            *(bf16x8*)&Bs[nb][(srl + 32) * 72 + sc8] = rB1;
        }
        __syncthreads();
    }
#pragma unroll
    for (int mi = 0; mi < 2; ++mi)
#pragma unroll
        for (int ni = 0; ni < 2; ++ni)
#pragma unroll
            for (int j = 0; j < 4; ++j) {
                int r = row0 + wm + mi * 16 + l4 * 4 + j;
                int c = col0 + wn + ni * 16 + l15;
                Cb[(size_t)r * N + c] = f2b(acc[mi][ni][j] + bias[c]);
            }
}

// ======= W2 GEMM with fused LayerNorm(512)+GELU on A-load =======
__global__ __launch_bounds__(256)
void gemm_w2ln(const u16* __restrict__ hb, const float* __restrict__ g,
               const float* __restrict__ be, const u16* __restrict__ Bt,
               const float* __restrict__ bias, float* __restrict__ xf,
               u16* __restrict__ xb) {
    __shared__ u16 As[2][64 * 72];
    __shared__ u16 Bs[2][64 * 72];
    __shared__ float muS[64], rsS[64];
    const int N = 256, K = 512;
    int tid = threadIdx.x;
    int lane = tid & 63, wave = tid >> 6;
    int row0 = blockIdx.y * 64, col0 = blockIdx.x * 64;
    int wm = (wave >> 1) * 32, wn = (wave & 1) * 32;
    int l15 = lane & 15, l4 = lane >> 4;
    f32x4 acc[2][2] = {};

    // --- LN stats: 4 threads per row, 128 elems each ---
    {
        int rr = tid >> 2, seg = tid & 3;
        const u16* hrow = hb + (size_t)(row0 + rr) * 512 + seg * 128;
        float sum = 0.f, ss = 0.f;
#pragma unroll
        for (int q = 0; q < 16; ++q) {
            bf16x8 v = *(const bf16x8*)&hrow[q * 8];
#pragma unroll
            for (int e = 0; e < 8; ++e) { float f = b2f(((u16*)&v)[e]); sum += f; ss += f * f; }
        }
        sum += __shfl_xor(sum, 1); ss += __shfl_xor(ss, 1);
        sum += __shfl_xor(sum, 2); ss += __shfl_xor(ss, 2);
        float mu = sum * (1.f / 512.f);
        float var = ss * (1.f / 512.f) - mu * mu;
        if (seg == 0) { muS[rr] = mu; rsS[rr] = rsqrtf(var + 1e-5f); }
    }
    __syncthreads();

    int srl = tid >> 3, sc8 = (tid & 7) * 8;
    auto ldA = [&](int k0, int it) -> bf16x8 {
        return *(const bf16x8*)&hb[(size_t)(row0 + srl + it * 32) * 512 + k0 + sc8];
    };
    auto ldB = [&](int k0, int it) -> bf16x8 {
        return *(const bf16x8*)&Bt[(size_t)(col0 + srl + it * 32) * K + k0 + sc8];
    };
    auto cook = [&](bf16x8 v, int it, int k0) -> bf16x8 {
        int r = srl + it * 32;
        float mu = muS[r], rs = rsS[r];
        u16 o[8];
#pragma unroll
        for (int e = 0; e < 8; ++e) {
            float y = (b2f(((u16*)&v)[e]) - mu) * rs * g[k0 + sc8 + e] + be[k0 + sc8 + e];
            o[e] = f2b(0.5f * y * (1.f + erff(y * 0.70710678118654752f)));
        }
        return *(bf16x8*)o;
    };

    bf16x8 rA0 = ldA(0, 0), rA1 = ldA(0, 1);
    bf16x8 rB0 = ldB(0, 0), rB1 = ldB(0, 1);
    *(bf16x8*)&As[0][srl * 72 + sc8] = cook(rA0, 0, 0);
    *(bf16x8*)&As[0][(srl + 32) * 72 + sc8] = cook(rA1, 1, 0);
    *(bf16x8*)&Bs[0][srl * 72 + sc8] = rB0;
    *(bf16x8*)&Bs[0][(srl + 32) * 72 + sc8] = rB1;
    __syncthreads();

    for (int t = 0; t < 8; ++t) {
        int buf = t & 1;
        bool more = (t + 1) < 8;
        if (more) {
            rA0 = ldA((t + 1) * 64, 0); rA1 = ldA((t + 1) * 64, 1);
            rB0 = ldB((t + 1) * 64, 0); rB1 = ldB((t + 1) * 64, 1);
        }
#pragma unroll
        for (int ks = 0; ks < 2; ++ks) {
            bf16x8 a0 = *(bf16x8*)&As[buf][(wm + l15) * 72 + ks * 32 + l4 * 8];
            bf16x8 a1 = *(bf16x8*)&As[buf][(wm + 16 + l15) * 72 + ks * 32 + l4 * 8];
            bf16x8 b0 = *(bf16x8*)&Bs[buf][(wn + l15) * 72 + ks * 32 + l4 * 8];
            bf16x8 b1 = *(bf16x8*)&Bs[buf][(wn + 16 + l15) * 72 + ks * 32 + l4 * 8];
            acc[0][0] = __builtin_amdgcn_mfma_f32_16x16x32_bf16(a0, b0, acc[0][0], 0, 0, 0);
            acc[0][1] = __builtin_amdgcn_mfma_f32_16x16x32_bf16(a0, b1, acc[0][1], 0, 0, 0);
            acc[1][0] = __builtin_amdgcn_mfma_f32_16x16x32_bf16(a1, b0, acc[1][0], 0, 0, 0);
            acc[1][1] = __builtin_amdgcn_mfma_f32_16x16x32_bf16(a1, b1, acc[1][1], 0, 0, 0);
        }
        if (more) {
            int nb = buf ^ 1;
            *(bf16x8*)&As[nb][srl * 72 + sc8] = cook(rA0, 0, (t + 1) * 64);
            *(bf16x8*)&As[nb][(srl + 32) * 72 + sc8] = cook(rA1, 1, (t + 1) * 64);
            *(bf16x8*)&Bs[nb][srl * 72 + sc8] = rB0;
            *(bf16x8*)&Bs[nb][(srl + 32) * 72 + sc8] = rB1;
        }
        __syncthreads();
    }
#pragma unroll
    for (int mi = 0; mi < 2; ++mi)
#pragma unroll
        for (int ni = 0; ni < 2; ++ni)
#pragma unroll
            for (int j = 0; j < 4; ++j) {
                int r = row0 + wm + mi * 16 + l4 * 4 + j;
                int c = col0 + wn + ni * 16 + l15;
                float v = acc[mi][ni][j] + bias[c] + xf[(size_t)r * N + c];
                xf[(size_t)r * N + c] = v;
                xb[(size_t)r * N + c] = f2b(v);
            }
}

// ======= flash attention, kv-split 2-way, dbuf K/V, tr-read V, hoisted Q =======
#define QSTR 72
#define VDSTR 1032
#define VBUFE (4 * VDSTR)

__global__ __launch_bounds__(256)
void flash_kernel(const u16* __restrict__ Qp, const u16* __restrict__ Vp,
                  float* __restrict__ Op, float* __restrict__ mp, float* __restrict__ lp,
                  int kswap) {
    __shared__ u16 Qs[64 * QSTR];
    __shared__ u16 Ks[2][64 * QSTR];
    __shared__ u16 Vs[2][VBUFE];
    __shared__ u16 Ps[64 * QSTR];
    int y = blockIdx.z;
    int half = blockIdx.y;
    int t = y >> 3, b = (y >> 2) & 1, h = y & 3;
    int qR = t * 2048 + b * 1024;
    int kt = kswap ? (1 - t) : t;
    int kR = kt * 2048 + b * 1024 + half * 512;
    int i0 = blockIdx.x * 64;
    int tid = threadIdx.x, lane = tid & 63, wave = tid >> 6;
    int l15 = lane & 15, l4 = lane >> 4;
    int wm = wave * 16;
    int srl = tid >> 3, sc8 = (tid & 7) * 8;

    const u16* Qbase = Qp + (size_t)(qR + i0) * 512 + h * 64;
    const u16* Kbase = Qp + (size_t)kR * 512 + h * 64;
    const u16* Vbase = Vp + (size_t)kR * 512 + h * 64;

#pragma unroll
    for (int it = 0; it < 2; ++it) {
        int rr = srl + it * 32;
        *(bf16x8*)&Qs[rr * QSTR + sc8] = *(const bf16x8*)&Qbase[(size_t)rr * 512 + sc8];
        *(bf16x8*)&Ks[0][rr * QSTR + sc8] = *(const bf16x8*)&Kbase[(size_t)rr * 512 + sc8];
        bf16x8 v = *(const bf16x8*)&Vbase[(size_t)rr * 512 + sc8];
        *(bf16x8*)&Vs[0][(sc8 >> 4) * VDSTR + rr * 16 + (sc8 & 15)] = v;
    }
    __syncthreads();

    bf16x8 qf[2];
    qf[0] = *(bf16x8*)&Qs[(wm + l15) * QSTR + l4 * 8];
    qf[1] = *(bf16x8*)&Qs[(wm + l15) * QSTR + 32 + l4 * 8];

    float m[4], l[4];
    f32x4 accO[4] = {};
#pragma unroll
    for (int j = 0; j < 4; ++j) { m[j] = -1e30f; l[j] = 0.f; }

    for (int j0 = 0; j0 < 512; j0 += 64) {
        int buf = (j0 >> 6) & 1;
        bool more = (j0 + 64) < 512;
        bf16x8 nK0, nK1, nV0, nV1;
        if (more) {
            nK0 = *(const bf16x8*)&Kbase[(size_t)(j0 + 64 + srl) * 512 + sc8];
            nK1 = *(const bf16x8*)&Kbase[(size_t)(j0 + 96 + srl) * 512 + sc8];
            nV0 = *(const bf16x8*)&Vbase[(size_t)(j0 + 64 + srl) * 512 + sc8];
            nV1 = *(const bf16x8*)&Vbase[(size_t)(j0 + 96 + srl) * 512 + sc8];
        }
        f32x4 accS[4] = {};
#pragma unroll
        for (int ks = 0; ks < 2; ++ks) {
#pragma unroll
            for (int n = 0; n < 4; ++n) {
                bf16x8 bb = *(bf16x8*)&Ks[buf][(n * 16 + l15) * QSTR + ks * 32 + l4 * 8];
                accS[n] = __builtin_amdgcn_mfma_f32_16x16x32_bf16(qf[ks], bb, accS[n], 0, 0, 0);
            }
        }
        float p[4][4];
#pragma unroll
        for (int j = 0; j < 4; ++j) {
            float tm = fmaxf(fmaxf(accS[0][j], accS[1][j]), fmaxf(accS[2][j], accS[3][j]));
#pragma unroll
            for (int d = 1; d < 16; d <<= 1) tm = fmaxf(tm, __shfl_xor(tm, d));
            float mnew = fmaxf(m[j], tm);
            float rr = __expf(m[j] - mnew);
            float ts = 0.f;
#pragma unroll
            for (int n = 0; n < 4; ++n) {
                float pv = __expf(accS[n][j] - mnew);
                p[n][j] = pv; ts += pv;
            }
#pragma unroll
            for (int d = 1; d < 16; d <<= 1) ts += __shfl_xor(ts, d);
            l[j] = l[j] * rr + ts;
            m[j] = mnew;
#pragma unroll
            for (int n = 0; n < 4; ++n) accO[n][j] *= rr;
        }
#pragma unroll
        for (int n = 0; n < 4; ++n) {
            int kv = n * 16 + l15;
            int c = (kv & 32) + (((kv >> 2) & 3) << 3) + (((kv >> 4) & 1) << 2) + (kv & 3);
#pragma unroll
            for (int j = 0; j < 4; ++j)
                Ps[(wm + l4 * 4 + j) * QSTR + c] = f2b(p[n][j]);
        }
#pragma unroll
        for (int ks = 0; ks < 2; ++ks) {
            bf16x8 a = *(bf16x8*)&Ps[(wm + l15) * QSTR + ks * 32 + l4 * 8];
#pragma unroll
            for (int n = 0; n < 4; ++n) {
                unsigned va = (unsigned)(size_t)(&Vs[buf][n * VDSTR]) + ks * 1024 + lane * 8;
                unsigned long long q0, q1;
                asm volatile("ds_read_b64_tr_b16 %0, %2\n\t"
                             "ds_read_b64_tr_b16 %1, %2 offset:512\n\t"
                             "s_waitcnt lgkmcnt(0)"
                             : "=&v"(q0), "=&v"(q1) : "v"(va) : "memory");
                union { unsigned long long q[2]; bf16x8 v; } uu;
                uu.q[0] = q0; uu.q[1] = q1;
                accO[n] = __builtin_amdgcn_mfma_f32_16x16x32_bf16(a, uu.v, accO[n], 0, 0, 0);
            }
        }
        if (more) {
            int nb = buf ^ 1;
            *(bf16x8*)&Ks[nb][srl * QSTR + sc8] = nK0;
            *(bf16x8*)&Ks[nb][(srl + 32) * QSTR + sc8] = nK1;
            *(bf16x8*)&Vs[nb][(sc8 >> 4) * VDSTR + srl * 16 + (sc8 & 15)] = nV0;
            *(bf16x8*)&Vs[nb][(sc8 >> 4) * VDSTR + (srl + 32) * 16 + (sc8 & 15)] = nV1;
        }
        __syncthreads();
    }
    size_t obase = (size_t)(half * 16 + y) * 1024 + i0;
#pragma unroll
    for (int n = 0; n < 4; ++n)
#pragma unroll
        for (int j = 0; j < 4; ++j) {
            int r = wm + l4 * 4 + j;
            Op[(obase + r) * 64 + n * 16 + l15] = accO[n][j];
        }
    if (l15 == 0) {
#pragma unroll
        for (int j = 0; j < 4; ++j) {
            int r = wm + l4 * 4 + j;
            mp[obase + r] = m[j];
            lp[obase + r] = l[j];
        }
    }
}

// ---------------- per-row max & sumexp ----------------
__global__ void rowstats_kernel(const float* __restrict__ S, float* __restrict__ rm,
                                float* __restrict__ rs, int ncols) {
    __shared__ float sb[256];
    int row = blockIdx.x, tid = threadIdx.x;
    const float* p = S + (size_t)row * ncols;
    float m = -1e30f;
    for (int j = tid; j < ncols; j += 256) m = fmaxf(m, p[j]);
    sb[tid] = m; __syncthreads();
    for (int s = 128; s > 0; s >>= 1) { if (tid < s) sb[tid] = fmaxf(sb[tid], sb[tid + s]); __syncthreads(); }
    m = sb[0]; __syncthreads();
    float s = 0;
    for (int j = tid; j < ncols; j += 256) s += __expf(p[j] - m);
    sb[tid] = s; __syncthreads();
    for (int st = 128; st > 0; st >>= 1) { if (tid < st) sb[tid] += sb[tid + st]; __syncthreads(); }
    if (tid == 0) { rm[row] = m; rs[row] = sb[0]; }
}

// ---------------- column stats: partial + reduce ----------------
#define CSCH 8
__global__ void colstats_part(const float* __restrict__ S, float* __restrict__ pm,
                              float* __restrict__ ps) {
    int mat = blockIdx.z;
    int j = blockIdx.x * 256 + threadIdx.x;
    int r0 = blockIdx.y * (NN / CSCH);
    const float* p = S + (size_t)mat * NN * NN + (size_t)r0 * NN + j;
    float m = -1e30f;
    for (int i = 0; i < NN / CSCH; ++i) m = fmaxf(m, p[(size_t)i * NN]);
    float s = 0;
    for (int i = 0; i < NN / CSCH; ++i) s += __expf(p[(size_t)i * NN] - m);
    int o = (mat * CSCH + blockIdx.y) * NN + j;
    pm[o] = m; ps[o] = s;
}
__global__ void colstats_red(const float* __restrict__ pm, const float* __restrict__ ps,
                             float* __restrict__ cm, float* __restrict__ cs) {
    int idx = blockIdx.x * 256 + threadIdx.x;
    int mat = idx >> 10, j = idx & 1023;
    float m = -1e30f;
#pragma unroll
    for (int k = 0; k < CSCH; ++k) m = fmaxf(m, pm[(mat * CSCH + k) * NN + j]);
    float s = 0;
#pragma unroll
    for (int k = 0; k < CSCH; ++k)
        s += ps[(mat * CSCH + k) * NN + j] * __expf(pm[(mat * CSCH + k) * NN + j] - m);
    cm[idx] = m; cs[idx] = s;
}

// ---------------- z = x @ Wm + bm ----------------
__global__ void zproj_kernel(const float* __restrict__ X, const float* __restrict__ Wm,
                             const float* __restrict__ bm, float* __restrict__ z) {
    __shared__ float sb[256];
    int row = blockIdx.x, tid = threadIdx.x;
    float v = X[(size_t)row * 256 + tid] * Wm[tid];
    sb[tid] = v; __syncthreads();
    for (int s = 128; s > 0; s >>= 1) { if (tid < s) sb[tid] += sb[tid + s]; __syncthreads(); }
    if (tid == 0) z[row] = sb[0] + bm[0];
}

// ---------------- final assemble ----------------
__global__ void assemble_kernel(const float* __restrict__ sim2, const float* __restrict__ z0,
                                const float* __restrict__ z1, const float* __restrict__ rm,
                                const float* __restrict__ rs, const float* __restrict__ cm,
                                const float* __restrict__ cs, float* __restrict__ out) {
    int idx = blockIdx.x * 256 + threadIdx.x;
    if (idx >= NB * NP * NP) return;
    int b = idx / (NP * NP);
    int rem = idx - b * NP * NP;
    int i = rem / NP, j = rem - i * NP;
    float v;
    if (i < NN && j < NN) {
        float s = sim2[((size_t)b * NN + i) * NN + j];
        float lr = s - rm[b * NN + i] - logf(rs[b * NN + i]);
        float lc = s - cm[b * NN + j] - logf(cs[b * NN + j]);
        v = lr + lc + logsigf(z0[b * NN + i]) + logsigf(z1[b * NN + j]);
    } else if (i < NN) {
        v = logsigf(-z0[b * NN + i]);
    } else if (j < NN) {
        v = logsigf(-z1[b * NN + j]);
    } else {
        v = 0.f;
    }
    out[idx] = v;
}

extern "C" void kernel_launch(void* const* d_in, const int* in_sizes, int n_in,
                              void* d_out, int out_size, void* d_ws, size_t ws_size,
                              hipStream_t stream) {
    auto in = [&](int i) { return (const float*)d_in[i]; };
    const float* kpts0 = in(0);
    const float* kpts1 = in(1);
    const float* desc0 = in(2);
    const float* desc1 = in(3);
    const float* fx = in(4);
    const float* fy = in(5);
    const float* sWqk = in(6);  const float* sbqk = in(7);
    const float* sWv  = in(8);  const float* sbv  = in(9);
    const float* sWo  = in(10); const float* sbo  = in(11);
    const float* sW1  = in(12); const float* sb1  = in(13);
    const float* sg   = in(14); const float* sbe  = in(15);
    const float* sW2  = in(16); const float* sb2  = in(17);
    const float* cWqk = in(18); const float* cbqk = in(19);
    const float* cWv  = in(20); const float* cbv  = in(21);
    const float* cWo  = in(22); const float* cbo  = in(23);
    const float* cW1  = in(24); const float* cb1  = in(25);
    const float* cg   = in(26); const float* cbe  = in(27);
    const float* cW2  = in(28); const float* cb2  = in(29);
    const float* Wp = in(30); const float* bp = in(31);
    const float* Wm = in(32); const float* bm = in(33);

    const int Mst = 2 * NB * NN;               // 4096 stacked rows
    const size_t SND = (size_t)Mst * ND;

    char* base = (char*)d_ws;
    size_t off = 0;
    auto allocf = [&](size_t n) { float* p = (float*)(base + off); off += ((n * 4 + 255) & ~(size_t)255); return p; };
    auto allocb = [&](size_t n) { u16* p = (u16*)(base + off);   off += ((n * 2 + 255) & ~(size_t)255); return p; };

    float* x    = allocf(SND);
    float* cst  = allocf((size_t)Mst * 64);
    float* snt  = allocf((size_t)Mst * 64);
    float* simb = allocf((size_t)NB * NN * NN);
    float* Opb  = allocf((size_t)2 * 16384 * 64);     // flash partials (2 halves)
    float* mpb  = allocf((size_t)2 * 16384);
    float* lpb  = allocf((size_t)2 * 16384);
    float* z    = allocf(Mst);
    float* st0  = allocf(2048);
    float* st1  = allocf(2048);
    float* st2  = allocf(2048);
    float* st3  = allocf(2048);
    float* pmb  = allocf((size_t)NB * CSCH * NN);
    float* psb  = allocf((size_t)NB * CSCH * NN);
    float* bqvs = allocf((size_t)NL * 512);
    float* bqvc = allocf((size_t)NL * 512);

    u16* xb    = allocb(SND);
    u16* tQVb  = allocb((size_t)Mst * 512);
    u16* attnb = allocb(SND);
    u16* mb    = allocb(SND);
    u16* hb    = allocb((size_t)Mst * 512);
    u16* wsqv = allocb((size_t)NL * 512 * 256);
    u16* wso  = allocb((size_t)NL * 256 * 256);
    u16* wsw1 = allocb((size_t)NL * 512 * 512);
    u16* wsw2 = allocb((size_t)NL * 512 * 256);
    u16* wcqv = allocb((size_t)NL * 512 * 256);
    u16* wco  = allocb((size_t)NL * 256 * 256);
    u16* wcw1 = allocb((size_t)NL * 512 * 512);
    u16* wcw2 = allocb((size_t)NL * 512 * 256);
    u16* wpb  = allocb((size_t)256 * 256);

    // ---- weight conversion: 4 launches ----
    {
        WP6 wa = {};
        wa.s[0] = sWqk; wa.d[0] = wsqv;             wa.oz[0] = 512 * 256;
        wa.s[1] = sWv;  wa.d[1] = wsqv + 256 * 256; wa.oz[1] = 512 * 256;
        wa.s[2] = sWo;  wa.d[2] = wso;              wa.oz[2] = 256 * 256;
        wa.s[3] = cWqk; wa.d[3] = wcqv;             wa.oz[3] = 512 * 256;
        wa.s[4] = cWv;  wa.d[4] = wcqv + 256 * 256; wa.oz[4] = 512 * 256;
        wa.s[5] = cWo;  wa.d[5] = wco;              wa.oz[5] = 256 * 256;
        wconvM_kernel<<<dim3(8, 8, 36), dim3(32, 8), 0, stream>>>(wa, 6, 256, 256);
        WP6 wb = {};
        wb.s[0] = sW1; wb.d[0] = wsw1; wb.oz[0] = 512 * 512;
        wb.s[1] = cW1; wb.d[1] = wcw1; wb.oz[1] = 512 * 512;
        wconvM_kernel<<<dim3(16, 16, 12), dim3(32, 8), 0, stream>>>(wb, 6, 512, 512);
        WP6 wc = {};
        wc.s[0] = sW2; wc.d[0] = wsw2; wc.oz[0] = 512 * 256;
        wc.s[1] = cW2; wc.d[1] = wcw2; wc.oz[1] = 512 * 256;
        wconvM_kernel<<<dim3(8, 16, 12), dim3(32, 8), 0, stream>>>(wc, 6, 512, 256);
        WP6 wd = {};
        wd.s[0] = Wp; wd.d[0] = wpb; wd.oz[0] = 256 * 256;
        wconvM_kernel<<<dim3(8, 8, 1), dim3(32, 8), 0, stream>>>(wd, 1, 256, 256);
    }
    biaspack_kernel<<<(NL * 512 + 255) / 256, 256, 0, stream>>>(sbqk, sbv, bqvs, NL);
    biaspack_kernel<<<(NL * 512 + 255) / 256, 256, 0, stream>>>(cbqk, cbv, bqvc, NL);

    rope_cs_kernel<<<1024, 256, 0, stream>>>(kpts0, kpts1, fx, fy, cst, snt);
    copyconv_kernel<<<4096, 256, 0, stream>>>(desc0, desc1, x, xb);

    auto gemm = [&](const u16* A, const u16* A2, const u16* Bt, const float* bias,
                    const float* res, float* Cf, u16* Cb, int M, int N, int K,
                    float slo, float shi, const float* csp, const float* snp) {
        gemm_mfma<<<dim3(N / 64, M / 64), 256, 0, stream>>>(A, A2, Bt, bias, res, Cf, Cb,
                                                            M, N, K, slo, shi, csp, snp);
    };

    const float sc = 0.35355339059327379f;   // DH^-0.25 per side

    for (int i = 0; i < NL; ++i) {
        const size_t oQV = (size_t)i * 512 * 256;
        const size_t oDD = (size_t)i * 256 * 256;
        const size_t oW1 = (size_t)i * 512 * 512;
        const size_t oW2 = (size_t)i * 512 * 256;

        // ---- self ----
        gemm(xb, nullptr, wsqv + oQV, bqvs + i * 512, nullptr, nullptr, tQVb,
             Mst, 512, 256, sc, 1.f, cst, snt);
        flash_kernel<<<dim3(16, 2, 16), 256, 0, stream>>>(tQVb, tQVb + 256, Opb, mpb, lpb, 0);
        gemm_oproj<<<dim3(4, 64), 256, 0, stream>>>(Opb, mpb, lpb, wso + oDD, sbo + i * ND, mb);
        gemm(xb, mb, wsw1 + oW1, sb1 + i * 512, nullptr, nullptr, hb,
             Mst, 512, 512, 1.f, 1.f, nullptr, nullptr);
        gemm_w2ln<<<dim3(4, 64), 256, 0, stream>>>(hb, sg + i * 512, sbe + i * 512,
                                                   wsw2 + oW2, sb2 + i * ND, x, xb);

        // ---- cross ----
        gemm(xb, nullptr, wcqv + oQV, bqvc + i * 512, nullptr, nullptr, tQVb,
             Mst, 512, 256, sc, 1.f, nullptr, nullptr);
        flash_kernel<<<dim3(16, 2, 16), 256, 0, stream>>>(tQVb, tQVb + 256, Opb, mpb, lpb, 1);
        gemm_oproj<<<dim3(4, 64), 256, 0, stream>>>(Opb, mpb, lpb, wco + oDD, cbo + i * ND, mb);
        gemm(xb, mb, wcw1 + oW1, cb1 + i * 512, nullptr, nullptr, hb,
             Mst, 512, 512, 1.f, 1.f, nullptr, nullptr);
        gemm_w2ln<<<dim3(4, 64), 256, 0, stream>>>(hb, cg + i * 512, cbe + i * 512,
                                                   wcw2 + oW2, cb2 + i * ND, x, xb);
    }

    // ---- match head ----
    gemm(xb, nullptr, wpb, bp, nullptr, nullptr, attnb,
         Mst, 256, 256, 0.25f, 0.25f, nullptr, nullptr);          // md stacked
    zproj_kernel<<<Mst, 256, 0, stream>>>(x, Wm, bm, z);
    for (int b = 0; b < NB; ++b) {
        gemm(attnb + (size_t)b * 1024 * 256, nullptr,
             attnb + (size_t)(2048 + b * 1024) * 256, nullptr, nullptr,
             simb + (size_t)b * NN * NN, nullptr,
             1024, 1024, 256, 1.f, 1.f, nullptr, nullptr);
    }
    rowstats_kernel<<<NB * NN, 256, 0, stream>>>(simb, st0, st1, NN);
    colstats_part<<<dim3(NN / 256, CSCH, NB), 256, 0, stream>>>(simb, pmb, psb);
    colstats_red<<<(NB * NN) / 256, 256, 0, stream>>>(pmb, psb, st2, st3);
    int total = NB * NP * NP;
    assemble_kernel<<<(total + 255) / 256, 256, 0, stream>>>(simb, z, z + 2048, st0, st1,
                                                             st2, st3, (float*)d_out);
}

// Round 6
// 1045.560 us; speedup vs baseline: 1.1526x; 1.1526x over previous
//
#include <hip/hip_runtime.h>
#include <hip/hip_bf16.h>
#include <math.h>

#define NB 2
#define NN 1024
#define ND 256
#define NL 6
#define NP (NN + 1)

typedef unsigned short u16;
typedef __attribute__((ext_vector_type(8))) short bf16x8;
typedef __attribute__((ext_vector_type(4))) float f32x4;

__device__ __forceinline__ u16 f2b(float f) {
    union { float f; unsigned u; } v; v.f = f;
    unsigned r = v.u + 0x7FFFu + ((v.u >> 16) & 1u);
    return (u16)(r >> 16);
}
__device__ __forceinline__ float b2f(u16 b) {
    union { unsigned u; float f; } v; v.u = ((unsigned)b) << 16;
    return v.f;
}
__device__ __forceinline__ float logsigf(float x) {
    return (x >= 0.f) ? -log1pf(expf(-x)) : (x - log1pf(expf(x)));
}

// ---------------- RoPE tables (both tensors, one launch) ----------------
__global__ void rope_cs_kernel(const float* __restrict__ k0p, const float* __restrict__ k1p,
                               const float* __restrict__ fx, const float* __restrict__ fy,
                               float* __restrict__ cs, float* __restrict__ sn) {
    int idx = blockIdx.x * 256 + threadIdx.x;      // 4096*64
    int row = idx >> 6, j = idx & 63;
    const float* kp = (row < 2048) ? k0p + (size_t)row * 2 : k1p + (size_t)(row - 2048) * 2;
    float kx = kp[0], ky = kp[1];
    float f;
    if (j < 32) f = ((kx - 512.f) * (1.f / 512.f)) * fx[j >> 1];
    else        f = ((ky - 384.f) * (1.f / 512.f)) * fy[(j - 32) >> 1];
    cs[idx] = cosf(f);
    sn[idx] = sinf(f);
}

// ---------------- copy both desc tensors + bf16 mirror ----------------
__global__ void copyconv_kernel(const float* __restrict__ d0, const float* __restrict__ d1,
                                float* __restrict__ outf, u16* __restrict__ outb) {
    int i = blockIdx.x * 256 + threadIdx.x;        // 2*524288
    float v = (i < 524288) ? d0[i] : d1[i - 524288];
    outf[i] = v; outb[i] = f2b(v);
}

// ------- multi-weight convert+transpose ----
struct WP6 {
    const float* s[6];
    u16* d[6];
    unsigned long long oz[6];
};
__global__ void wconvM_kernel(WP6 w, int perT, int K, int N) {
    __shared__ float t[32][33];
    int z = blockIdx.z;
    int p = z / perT, l = z - p * perT;
    const float* W = w.s[p] + (size_t)l * K * N;
    u16* Wt = w.d[p] + (size_t)l * w.oz[p];
    int k0 = blockIdx.y * 32, n0 = blockIdx.x * 32;
    int tx = threadIdx.x, ty = threadIdx.y;  // 32 x 8
    for (int i = 0; i < 32; i += 8)
        t[ty + i][tx] = W[(size_t)(k0 + ty + i) * N + n0 + tx];
    __syncthreads();
    for (int i = 0; i < 32; i += 8)
        Wt[(size_t)(n0 + ty + i) * K + k0 + tx] = f2b(t[tx][ty + i]);
}

__global__ void biaspack_kernel(const float* __restrict__ b0, const float* __restrict__ b1,
                                float* __restrict__ out, int L) {
    int idx = blockIdx.x * 256 + threadIdx.x;
    if (idx >= L * 512) return;
    int i = idx >> 9, c = idx & 511;
    out[idx] = (c < 256) ? b0[i * 256 + c] : b1[i * 256 + c - 256];
}

// ======= generic GEMM: BK=64, double-buffered LDS, one barrier/iter =======
__global__ __launch_bounds__(256)
void gemm_mfma(const u16* __restrict__ A, const u16* __restrict__ A2,
               const u16* __restrict__ Bt, const float* __restrict__ bias,
               const float* __restrict__ res, float* __restrict__ Cf, u16* __restrict__ Cb,
               int M, int N, int K, float scale_lo, float scale_hi,
               const float* __restrict__ csp, const float* __restrict__ snp) {
    __shared__ u16 As[2][64 * 72];
    __shared__ u16 Bs[2][64 * 72];
    int tid = threadIdx.x;
    int lane = tid & 63, wave = tid >> 6;
    int row0 = blockIdx.y * 64, col0 = blockIdx.x * 64;
    int wm = (wave >> 1) * 32, wn = (wave & 1) * 32;
    int l15 = lane & 15, l4 = lane >> 4;
    f32x4 acc[2][2] = {};
    int srl = tid >> 3, sc8 = (tid & 7) * 8;

    auto loadA = [&](int k0, int it) -> bf16x8 {
        int rr = row0 + srl + it * 32;
        int kg = k0 + sc8;
        const u16* src;
        if (A2) src = (kg < 256) ? &A[(size_t)rr * 256 + kg] : &A2[(size_t)rr * 256 + kg - 256];
        else    src = &A[(size_t)rr * K + kg];
        return *(const bf16x8*)src;
    };
    auto loadB = [&](int k0, int it) -> bf16x8 {
        return *(const bf16x8*)&Bt[(size_t)(col0 + srl + it * 32) * K + k0 + sc8];
    };

    bf16x8 rA0 = loadA(0, 0), rA1 = loadA(0, 1);
    bf16x8 rB0 = loadB(0, 0), rB1 = loadB(0, 1);
    *(bf16x8*)&As[0][srl * 72 + sc8] = rA0;
    *(bf16x8*)&As[0][(srl + 32) * 72 + sc8] = rA1;
    *(bf16x8*)&Bs[0][srl * 72 + sc8] = rB0;
    *(bf16x8*)&Bs[0][(srl + 32) * 72 + sc8] = rB1;
    __syncthreads();

    int nt = K >> 6;
    for (int t = 0; t < nt; ++t) {
        int buf = t & 1;
        bool more = (t + 1) < nt;
        if (more) {
            rA0 = loadA((t + 1) * 64, 0); rA1 = loadA((t + 1) * 64, 1);
            rB0 = loadB((t + 1) * 64, 0); rB1 = loadB((t + 1) * 64, 1);
        }
#pragma unroll
        for (int ks = 0; ks < 2; ++ks) {
            bf16x8 a0 = *(bf16x8*)&As[buf][(wm + l15) * 72 + ks * 32 + l4 * 8];
            bf16x8 a1 = *(bf16x8*)&As[buf][(wm + 16 + l15) * 72 + ks * 32 + l4 * 8];
            bf16x8 b0 = *(bf16x8*)&Bs[buf][(wn + l15) * 72 + ks * 32 + l4 * 8];
            bf16x8 b1 = *(bf16x8*)&Bs[buf][(wn + 16 + l15) * 72 + ks * 32 + l4 * 8];
            acc[0][0] = __builtin_amdgcn_mfma_f32_16x16x32_bf16(a0, b0, acc[0][0], 0, 0, 0);
            acc[0][1] = __builtin_amdgcn_mfma_f32_16x16x32_bf16(a0, b1, acc[0][1], 0, 0, 0);
            acc[1][0] = __builtin_amdgcn_mfma_f32_16x16x32_bf16(a1, b0, acc[1][0], 0, 0, 0);
            acc[1][1] = __builtin_amdgcn_mfma_f32_16x16x32_bf16(a1, b1, acc[1][1], 0, 0, 0);
        }
        if (more) {
            int nb = buf ^ 1;
            *(bf16x8*)&As[nb][srl * 72 + sc8] = rA0;
            *(bf16x8*)&As[nb][(srl + 32) * 72 + sc8] = rA1;
            *(bf16x8*)&Bs[nb][srl * 72 + sc8] = rB0;
            *(bf16x8*)&Bs[nb][(srl + 32) * 72 + sc8] = rB1;
        }
        __syncthreads();
    }
#pragma unroll
    for (int mi = 0; mi < 2; ++mi)
#pragma unroll
        for (int ni = 0; ni < 2; ++ni)
#pragma unroll
            for (int j = 0; j < 4; ++j) {
                int r = row0 + wm + mi * 16 + l4 * 4 + j;
                int c = col0 + wn + ni * 16 + l15;
                float v = acc[mi][ni][j] + (bias ? bias[c] : 0.f);
                float pn = __shfl_xor(v, 1);
                if (csp && c < 256) {
                    float cc = csp[(size_t)r * 64 + (c & 63)];
                    float ss = snp[(size_t)r * 64 + (c & 63)];
                    v = (c & 1) ? (v * cc + pn * ss) : (v * cc - pn * ss);
                }
                v *= (c < 256) ? scale_lo : scale_hi;
                if (res) v += res[(size_t)r * N + c];
                if (Cf) Cf[(size_t)r * N + c] = v;
                if (Cb) Cb[(size_t)r * N + c] = f2b(v);
            }
}

// ======= O-proj GEMM with fused flash-partial combine on A-load =======
__global__ __launch_bounds__(256)
void gemm_oproj(const float* __restrict__ Op, const float* __restrict__ mp,
                const float* __restrict__ lp, const u16* __restrict__ Bt,
                const float* __restrict__ bias, u16* __restrict__ Cb) {
    __shared__ u16 As[2][64 * 72];
    __shared__ u16 Bs[2][64 * 72];
    const int N = 256, K = 256;
    int tid = threadIdx.x;
    int lane = tid & 63, wave = tid >> 6;
    int row0 = blockIdx.y * 64, col0 = blockIdx.x * 64;
    int wm = (wave >> 1) * 32, wn = (wave & 1) * 32;
    int l15 = lane & 15, l4 = lane >> 4;
    f32x4 acc[2][2] = {};
    int srl = tid >> 3, sc8 = (tid & 7) * 8;

    auto loadA = [&](int k0, int it) -> bf16x8 {
        int rg = row0 + srl + it * 32;
        int kg = k0 + sc8;
        int h = kg >> 6, d0 = kg & 63;
        int t = rg >> 11, bb = (rg >> 10) & 1, iq = rg & 1023;
        int y = t * 8 + bb * 4 + h;
        int ri = y * 1024 + iq;
        size_t base0 = (size_t)ri * 64 + d0;
        size_t base1 = base0 + (size_t)16384 * 64;
        f32x4 a0 = *(const f32x4*)&Op[base0];
        f32x4 a1 = *(const f32x4*)&Op[base0 + 4];
        f32x4 c0 = *(const f32x4*)&Op[base1];
        f32x4 c1 = *(const f32x4*)&Op[base1 + 4];
        float m0 = mp[ri], m1 = mp[16384 + ri];
        float l0 = lp[ri], l1 = lp[16384 + ri];
        float mf = fmaxf(m0, m1);
        float e0 = __expf(m0 - mf), e1 = __expf(m1 - mf);
        float inv = 1.f / (l0 * e0 + l1 * e1);
        e0 *= inv; e1 *= inv;
        u16 o[8];
#pragma unroll
        for (int e = 0; e < 4; ++e) {
            o[e] = f2b(a0[e] * e0 + c0[e] * e1);
            o[4 + e] = f2b(a1[e] * e0 + c1[e] * e1);
        }
        return *(bf16x8*)o;
    };
    auto loadB = [&](int k0, int it) -> bf16x8 {
        return *(const bf16x8*)&Bt[(size_t)(col0 + srl + it * 32) * K + k0 + sc8];
    };

    bf16x8 rA0 = loadA(0, 0), rA1 = loadA(0, 1);
    bf16x8 rB0 = loadB(0, 0), rB1 = loadB(0, 1);
    *(bf16x8*)&As[0][srl * 72 + sc8] = rA0;
    *(bf16x8*)&As[0][(srl + 32) * 72 + sc8] = rA1;
    *(bf16x8*)&Bs[0][srl * 72 + sc8] = rB0;
    *(bf16x8*)&Bs[0][(srl + 32) * 72 + sc8] = rB1;
    __syncthreads();

    for (int t = 0; t < 4; ++t) {
        int buf = t & 1;
        bool more = (t + 1) < 4;
        if (more) {
            rA0 = loadA((t + 1) * 64, 0); rA1 = loadA((t + 1) * 64, 1);
            rB0 = loadB((t + 1) * 64, 0); rB1 = loadB((t + 1) * 64, 1);
        }
#pragma unroll
        for (int ks = 0; ks < 2; ++ks) {
            bf16x8 a0 = *(bf16x8*)&As[buf][(wm + l15) * 72 + ks * 32 + l4 * 8];
            bf16x8 a1 = *(bf16x8*)&As[buf][(wm + 16 + l15) * 72 + ks * 32 + l4 * 8];
            bf16x8 b0 = *(bf16x8*)&Bs[buf][(wn + l15) * 72 + ks * 32 + l4 * 8];
            bf16x8 b1 = *(bf16x8*)&Bs[buf][(wn + 16 + l15) * 72 + ks * 32 + l4 * 8];
            acc[0][0] = __builtin_amdgcn_mfma_f32_16x16x32_bf16(a0, b0, acc[0][0], 0, 0, 0);
            acc[0][1] = __builtin_amdgcn_mfma_f32_16x16x32_bf16(a0, b1, acc[0][1], 0, 0, 0);
            acc[1][0] = __builtin_amdgcn_mfma_f32_16x16x32_bf16(a1, b0, acc[1][0], 0, 0, 0);
            acc[1][1] = __builtin_amdgcn_mfma_f32_16x16x32_bf16(a1, b1, acc[1][1], 0, 0, 0);
        }
        if (more) {
            int nb = buf ^ 1;
            *(bf16x8*)&As[nb][srl * 72 + sc8] = rA0;
            *(bf16x8*)&As[nb][(srl + 32) * 72 + sc8] = rA1;
            *(bf16x8*)&Bs[nb][srl * 72 + sc8] = rB0;
            *(bf16x8*)&Bs[nb][(srl + 32) * 72 + sc8] = rB1;
        }
        __syncthreads();
    }
#pragma unroll
    for (int mi = 0; mi < 2; ++mi)
#pragma unroll
        for (int ni = 0; ni < 2; ++ni)
#pragma unroll
            for (int j = 0; j < 4; ++j) {
                int r = row0 + wm + mi * 16 + l4 * 4 + j;
                int c = col0 + wn + ni * 16 + l15;
                Cb[(size_t)r * N + c] = f2b(acc[mi][ni][j] + bias[c]);
            }
}

// ======= LN(512)+GELU: one wave per row, fully vectorized, no barriers =======
__global__ __launch_bounds__(256)
void ln_gelu_wave(const u16* __restrict__ hb, const float* __restrict__ g,
                  const float* __restrict__ be, u16* __restrict__ out) {
    int wave = threadIdx.x >> 6, lane = threadIdx.x & 63;
    int row = blockIdx.x * 4 + wave;
    const u16* p = hb + (size_t)row * 512 + lane * 8;
    bf16x8 v = *(const bf16x8*)p;
    float f[8];
    float sum = 0.f, ss = 0.f;
#pragma unroll
    for (int e = 0; e < 8; ++e) {
        f[e] = b2f(((u16*)&v)[e]);
        sum += f[e]; ss += f[e] * f[e];
    }
#pragma unroll
    for (int d = 1; d < 64; d <<= 1) {
        sum += __shfl_xor(sum, d);
        ss  += __shfl_xor(ss, d);
    }
    float mu = sum * (1.f / 512.f);
    float rstd = rsqrtf(ss * (1.f / 512.f) - mu * mu + 1e-5f);
    f32x4 g0 = *(const f32x4*)&g[lane * 8];
    f32x4 g1 = *(const f32x4*)&g[lane * 8 + 4];
    f32x4 b0 = *(const f32x4*)&be[lane * 8];
    f32x4 b1 = *(const f32x4*)&be[lane * 8 + 4];
    u16 o[8];
#pragma unroll
    for (int e = 0; e < 8; ++e) {
        float gg = (e < 4) ? g0[e] : g1[e - 4];
        float bb = (e < 4) ? b0[e] : b1[e - 4];
        float y = (f[e] - mu) * rstd * gg + bb;
        o[e] = f2b(0.5f * y * (1.f + erff(y * 0.70710678118654752f)));
    }
    *(bf16x8*)(out + (size_t)row * 512 + lane * 8) = *(bf16x8*)o;
}

// ======= flash attention, kv-split 2-way, dbuf K/V, tr-read V, hoisted Q =======
#define QSTR 72
#define VDSTR 1032
#define VBUFE (4 * VDSTR)

__global__ __launch_bounds__(256)
void flash_kernel(const u16* __restrict__ Qp, const u16* __restrict__ Vp,
                  float* __restrict__ Op, float* __restrict__ mp, float* __restrict__ lp,
                  int kswap) {
    __shared__ u16 Qs[64 * QSTR];
    __shared__ u16 Ks[2][64 * QSTR];
    __shared__ u16 Vs[2][VBUFE];
    __shared__ u16 Ps[64 * QSTR];
    int y = blockIdx.z;
    int half = blockIdx.y;
    int t = y >> 3, b = (y >> 2) & 1, h = y & 3;
    int qR = t * 2048 + b * 1024;
    int kt = kswap ? (1 - t) : t;
    int kR = kt * 2048 + b * 1024 + half * 512;
    int i0 = blockIdx.x * 64;
    int tid = threadIdx.x, lane = tid & 63, wave = tid >> 6;
    int l15 = lane & 15, l4 = lane >> 4;
    int wm = wave * 16;
    int srl = tid >> 3, sc8 = (tid & 7) * 8;

    const u16* Qbase = Qp + (size_t)(qR + i0) * 512 + h * 64;
    const u16* Kbase = Qp + (size_t)kR * 512 + h * 64;
    const u16* Vbase = Vp + (size_t)kR * 512 + h * 64;

#pragma unroll
    for (int it = 0; it < 2; ++it) {
        int rr = srl + it * 32;
        *(bf16x8*)&Qs[rr * QSTR + sc8] = *(const bf16x8*)&Qbase[(size_t)rr * 512 + sc8];
        *(bf16x8*)&Ks[0][rr * QSTR + sc8] = *(const bf16x8*)&Kbase[(size_t)rr * 512 + sc8];
        bf16x8 v = *(const bf16x8*)&Vbase[(size_t)rr * 512 + sc8];
        *(bf16x8*)&Vs[0][(sc8 >> 4) * VDSTR + rr * 16 + (sc8 & 15)] = v;
    }
    __syncthreads();

    bf16x8 qf[2];
    qf[0] = *(bf16x8*)&Qs[(wm + l15) * QSTR + l4 * 8];
    qf[1] = *(bf16x8*)&Qs[(wm + l15) * QSTR + 32 + l4 * 8];

    float m[4], l[4];
    f32x4 accO[4] = {};
#pragma unroll
    for (int j = 0; j < 4; ++j) { m[j] = -1e30f; l[j] = 0.f; }

    for (int j0 = 0; j0 < 512; j0 += 64) {
        int buf = (j0 >> 6) & 1;
        bool more = (j0 + 64) < 512;
        bf16x8 nK0, nK1, nV0, nV1;
        if (more) {
            nK0 = *(const bf16x8*)&Kbase[(size_t)(j0 + 64 + srl) * 512 + sc8];
            nK1 = *(const bf16x8*)&Kbase[(size_t)(j0 + 96 + srl) * 512 + sc8];
            nV0 = *(const bf16x8*)&Vbase[(size_t)(j0 + 64 + srl) * 512 + sc8];
            nV1 = *(const bf16x8*)&Vbase[(size_t)(j0 + 96 + srl) * 512 + sc8];
        }
        f32x4 accS[4] = {};
#pragma unroll
        for (int ks = 0; ks < 2; ++ks) {
#pragma unroll
            for (int n = 0; n < 4; ++n) {
                bf16x8 bb = *(bf16x8*)&Ks[buf][(n * 16 + l15) * QSTR + ks * 32 + l4 * 8];
                accS[n] = __builtin_amdgcn_mfma_f32_16x16x32_bf16(qf[ks], bb, accS[n], 0, 0, 0);
            }
        }
        float p[4][4];
#pragma unroll
        for (int j = 0; j < 4; ++j) {
            float tm = fmaxf(fmaxf(accS[0][j], accS[1][j]), fmaxf(accS[2][j], accS[3][j]));
#pragma unroll
            for (int d = 1; d < 16; d <<= 1) tm = fmaxf(tm, __shfl_xor(tm, d));
            float mnew = fmaxf(m[j], tm);
            float rr = __expf(m[j] - mnew);
            float ts = 0.f;
#pragma unroll
            for (int n = 0; n < 4; ++n) {
                float pv = __expf(accS[n][j] - mnew);
                p[n][j] = pv; ts += pv;
            }
#pragma unroll
            for (int d = 1; d < 16; d <<= 1) ts += __shfl_xor(ts, d);
            l[j] = l[j] * rr + ts;
            m[j] = mnew;
#pragma unroll
            for (int n = 0; n < 4; ++n) accO[n][j] *= rr;
        }
#pragma unroll
        for (int n = 0; n < 4; ++n) {
            int kv = n * 16 + l15;
            int c = (kv & 32) + (((kv >> 2) & 3) << 3) + (((kv >> 4) & 1) << 2) + (kv & 3);
#pragma unroll
            for (int j = 0; j < 4; ++j)
                Ps[(wm + l4 * 4 + j) * QSTR + c] = f2b(p[n][j]);
        }
#pragma unroll
        for (int ks = 0; ks < 2; ++ks) {
            bf16x8 a = *(bf16x8*)&Ps[(wm + l15) * QSTR + ks * 32 + l4 * 8];
#pragma unroll
            for (int n = 0; n < 4; ++n) {
                unsigned va = (unsigned)(size_t)(&Vs[buf][n * VDSTR]) + ks * 1024 + lane * 8;
                unsigned long long q0, q1;
                asm volatile("ds_read_b64_tr_b16 %0, %2\n\t"
                             "ds_read_b64_tr_b16 %1, %2 offset:512\n\t"
                             "s_waitcnt lgkmcnt(0)"
                             : "=&v"(q0), "=&v"(q1) : "v"(va) : "memory");
                union { unsigned long long q[2]; bf16x8 v; } uu;
                uu.q[0] = q0; uu.q[1] = q1;
                accO[n] = __builtin_amdgcn_mfma_f32_16x16x32_bf16(a, uu.v, accO[n], 0, 0, 0);
            }
        }
        if (more) {
            int nb = buf ^ 1;
            *(bf16x8*)&Ks[nb][srl * QSTR + sc8] = nK0;
            *(bf16x8*)&Ks[nb][(srl + 32) * QSTR + sc8] = nK1;
            *(bf16x8*)&Vs[nb][(sc8 >> 4) * VDSTR + srl * 16 + (sc8 & 15)] = nV0;
            *(bf16x8*)&Vs[nb][(sc8 >> 4) * VDSTR + (srl + 32) * 16 + (sc8 & 15)] = nV1;
        }
        __syncthreads();
    }
    size_t obase = (size_t)(half * 16 + y) * 1024 + i0;
#pragma unroll
    for (int n = 0; n < 4; ++n)
#pragma unroll
        for (int j = 0; j < 4; ++j) {
            int r = wm + l4 * 4 + j;
            Op[(obase + r) * 64 + n * 16 + l15] = accO[n][j];
        }
    if (l15 == 0) {
#pragma unroll
        for (int j = 0; j < 4; ++j) {
            int r = wm + l4 * 4 + j;
            mp[obase + r] = m[j];
            lp[obase + r] = l[j];
        }
    }
}

// ---------------- per-row max & sumexp ----------------
__global__ void rowstats_kernel(const float* __restrict__ S, float* __restrict__ rm,
                                float* __restrict__ rs, int ncols) {
    __shared__ float sb[256];
    int row = blockIdx.x, tid = threadIdx.x;
    const float* p = S + (size_t)row * ncols;
    float m = -1e30f;
    for (int j = tid; j < ncols; j += 256) m = fmaxf(m, p[j]);
    sb[tid] = m; __syncthreads();
    for (int s = 128; s > 0; s >>= 1) { if (tid < s) sb[tid] = fmaxf(sb[tid], sb[tid + s]); __syncthreads(); }
    m = sb[0]; __syncthreads();
    float s = 0;
    for (int j = tid; j < ncols; j += 256) s += __expf(p[j] - m);
    sb[tid] = s; __syncthreads();
    for (int st = 128; st > 0; st >>= 1) { if (tid < st) sb[tid] += sb[tid + st]; __syncthreads(); }
    if (tid == 0) { rm[row] = m; rs[row] = sb[0]; }
}

// ---------------- column stats: partial + reduce ----------------
#define CSCH 8
__global__ void colstats_part(const float* __restrict__ S, float* __restrict__ pm,
                              float* __restrict__ ps) {
    int mat = blockIdx.z;
    int j = blockIdx.x * 256 + threadIdx.x;
    int r0 = blockIdx.y * (NN / CSCH);
    const float* p = S + (size_t)mat * NN * NN + (size_t)r0 * NN + j;
    float m = -1e30f;
    for (int i = 0; i < NN / CSCH; ++i) m = fmaxf(m, p[(size_t)i * NN]);
    float s = 0;
    for (int i = 0; i < NN / CSCH; ++i) s += __expf(p[(size_t)i * NN] - m);
    int o = (mat * CSCH + blockIdx.y) * NN + j;
    pm[o] = m; ps[o] = s;
}
__global__ void colstats_red(const float* __restrict__ pm, const float* __restrict__ ps,
                             float* __restrict__ cm, float* __restrict__ cs) {
    int idx = blockIdx.x * 256 + threadIdx.x;
    int mat = idx >> 10, j = idx & 1023;
    float m = -1e30f;
#pragma unroll
    for (int k = 0; k < CSCH; ++k) m = fmaxf(m, pm[(mat * CSCH + k) * NN + j]);
    float s = 0;
#pragma unroll
    for (int k = 0; k < CSCH; ++k)
        s += ps[(mat * CSCH + k) * NN + j] * __expf(pm[(mat * CSCH + k) * NN + j] - m);
    cm[idx] = m; cs[idx] = s;
}

// ---------------- z = x @ Wm + bm ----------------
__global__ void zproj_kernel(const float* __restrict__ X, const float* __restrict__ Wm,
                             const float* __restrict__ bm, float* __restrict__ z) {
    __shared__ float sb[256];
    int row = blockIdx.x, tid = threadIdx.x;
    float v = X[(size_t)row * 256 + tid] * Wm[tid];
    sb[tid] = v; __syncthreads();
    for (int s = 128; s > 0; s >>= 1) { if (tid < s) sb[tid] += sb[tid + s]; __syncthreads(); }
    if (tid == 0) z[row] = sb[0] + bm[0];
}

// ---------------- final assemble ----------------
__global__ void assemble_kernel(const float* __restrict__ sim2, const float* __restrict__ z0,
                                const float* __restrict__ z1, const float* __restrict__ rm,
                                const float* __restrict__ rs, const float* __restrict__ cm,
                                const float* __restrict__ cs, float* __restrict__ out) {
    int idx = blockIdx.x * 256 + threadIdx.x;
    if (idx >= NB * NP * NP) return;
    int b = idx / (NP * NP);
    int rem = idx - b * NP * NP;
    int i = rem / NP, j = rem - i * NP;
    float v;
    if (i < NN && j < NN) {
        float s = sim2[((size_t)b * NN + i) * NN + j];
        float lr = s - rm[b * NN + i] - logf(rs[b * NN + i]);
        float lc = s - cm[b * NN + j] - logf(cs[b * NN + j]);
        v = lr + lc + logsigf(z0[b * NN + i]) + logsigf(z1[b * NN + j]);
    } else if (i < NN) {
        v = logsigf(-z0[b * NN + i]);
    } else if (j < NN) {
        v = logsigf(-z1[b * NN + j]);
    } else {
        v = 0.f;
    }
    out[idx] = v;
}

extern "C" void kernel_launch(void* const* d_in, const int* in_sizes, int n_in,
                              void* d_out, int out_size, void* d_ws, size_t ws_size,
                              hipStream_t stream) {
    auto in = [&](int i) { return (const float*)d_in[i]; };
    const float* kpts0 = in(0);
    const float* kpts1 = in(1);
    const float* desc0 = in(2);
    const float* desc1 = in(3);
    const float* fx = in(4);
    const float* fy = in(5);
    const float* sWqk = in(6);  const float* sbqk = in(7);
    const float* sWv  = in(8);  const float* sbv  = in(9);
    const float* sWo  = in(10); const float* sbo  = in(11);
    const float* sW1  = in(12); const float* sb1  = in(13);
    const float* sg   = in(14); const float* sbe  = in(15);
    const float* sW2  = in(16); const float* sb2  = in(17);
    const float* cWqk = in(18); const float* cbqk = in(19);
    const float* cWv  = in(20); const float* cbv  = in(21);
    const float* cWo  = in(22); const float* cbo  = in(23);
    const float* cW1  = in(24); const float* cb1  = in(25);
    const float* cg   = in(26); const float* cbe  = in(27);
    const float* cW2  = in(28); const float* cb2  = in(29);
    const float* Wp = in(30); const float* bp = in(31);
    const float* Wm = in(32); const float* bm = in(33);

    const int Mst = 2 * NB * NN;               // 4096 stacked rows
    const size_t SND = (size_t)Mst * ND;

    char* base = (char*)d_ws;
    size_t off = 0;
    auto allocf = [&](size_t n) { float* p = (float*)(base + off); off += ((n * 4 + 255) & ~(size_t)255); return p; };
    auto allocb = [&](size_t n) { u16* p = (u16*)(base + off);   off += ((n * 2 + 255) & ~(size_t)255); return p; };

    float* x    = allocf(SND);
    float* cst  = allocf((size_t)Mst * 64);
    float* snt  = allocf((size_t)Mst * 64);
    float* simb = allocf((size_t)NB * NN * NN);
    float* Opb  = allocf((size_t)2 * 16384 * 64);     // flash partials (2 halves)
    float* mpb  = allocf((size_t)2 * 16384);
    float* lpb  = allocf((size_t)2 * 16384);
    float* z    = allocf(Mst);
    float* st0  = allocf(2048);
    float* st1  = allocf(2048);
    float* st2  = allocf(2048);
    float* st3  = allocf(2048);
    float* pmb  = allocf((size_t)NB * CSCH * NN);
    float* psb  = allocf((size_t)NB * CSCH * NN);
    float* bqvs = allocf((size_t)NL * 512);
    float* bqvc = allocf((size_t)NL * 512);

    u16* xb    = allocb(SND);
    u16* tQVb  = allocb((size_t)Mst * 512);
    u16* attnb = allocb(SND);
    u16* mb    = allocb(SND);
    u16* hb    = allocb((size_t)Mst * 512);
    u16* hgb   = allocb((size_t)Mst * 512);
    u16* wsqv = allocb((size_t)NL * 512 * 256);
    u16* wso  = allocb((size_t)NL * 256 * 256);
    u16* wsw1 = allocb((size_t)NL * 512 * 512);
    u16* wsw2 = allocb((size_t)NL * 512 * 256);
    u16* wcqv = allocb((size_t)NL * 512 * 256);
    u16* wco  = allocb((size_t)NL * 256 * 256);
    u16* wcw1 = allocb((size_t)NL * 512 * 512);
    u16* wcw2 = allocb((size_t)NL * 512 * 256);
    u16* wpb  = allocb((size_t)256 * 256);

    // ---- weight conversion: 4 launches ----
    {
        WP6 wa = {};
        wa.s[0] = sWqk; wa.d[0] = wsqv;             wa.oz[0] = 512 * 256;
        wa.s[1] = sWv;  wa.d[1] = wsqv + 256 * 256; wa.oz[1] = 512 * 256;
        wa.s[2] = sWo;  wa.d[2] = wso;              wa.oz[2] = 256 * 256;
        wa.s[3] = cWqk; wa.d[3] = wcqv;             wa.oz[3] = 512 * 256;
        wa.s[4] = cWv;  wa.d[4] = wcqv + 256 * 256; wa.oz[4] = 512 * 256;
        wa.s[5] = cWo;  wa.d[5] = wco;              wa.oz[5] = 256 * 256;
        wconvM_kernel<<<dim3(8, 8, 36), dim3(32, 8), 0, stream>>>(wa, 6, 256, 256);
        WP6 wb = {};
        wb.s[0] = sW1; wb.d[0] = wsw1; wb.oz[0] = 512 * 512;
        wb.s[1] = cW1; wb.d[1] = wcw1; wb.oz[1] = 512 * 512;
        wconvM_kernel<<<dim3(16, 16, 12), dim3(32, 8), 0, stream>>>(wb, 6, 512, 512);
        WP6 wc = {};
        wc.s[0] = sW2; wc.d[0] = wsw2; wc.oz[0] = 512 * 256;
        wc.s[1] = cW2; wc.d[1] = wcw2; wc.oz[1] = 512 * 256;
        wconvM_kernel<<<dim3(8, 16, 12), dim3(32, 8), 0, stream>>>(wc, 6, 512, 256);
        WP6 wd = {};
        wd.s[0] = Wp; wd.d[0] = wpb; wd.oz[0] = 256 * 256;
        wconvM_kernel<<<dim3(8, 8, 1), dim3(32, 8), 0, stream>>>(wd, 1, 256, 256);
    }
    biaspack_kernel<<<(NL * 512 + 255) / 256, 256, 0, stream>>>(sbqk, sbv, bqvs, NL);
    biaspack_kernel<<<(NL * 512 + 255) / 256, 256, 0, stream>>>(cbqk, cbv, bqvc, NL);

    rope_cs_kernel<<<1024, 256, 0, stream>>>(kpts0, kpts1, fx, fy, cst, snt);
    copyconv_kernel<<<4096, 256, 0, stream>>>(desc0, desc1, x, xb);

    auto gemm = [&](const u16* A, const u16* A2, const u16* Bt, const float* bias,
                    const float* res, float* Cf, u16* Cb, int M, int N, int K,
                    float slo, float shi, const float* csp, const float* snp) {
        gemm_mfma<<<dim3(N / 64, M / 64), 256, 0, stream>>>(A, A2, Bt, bias, res, Cf, Cb,
                                                            M, N, K, slo, shi, csp, snp);
    };

    const float sc = 0.35355339059327379f;   // DH^-0.25 per side

    for (int i = 0; i < NL; ++i) {
        const size_t oQV = (size_t)i * 512 * 256;
        const size_t oDD = (size_t)i * 256 * 256;
        const size_t oW1 = (size_t)i * 512 * 512;
        const size_t oW2 = (size_t)i * 512 * 256;

        // ---- self ----
        gemm(xb, nullptr, wsqv + oQV, bqvs + i * 512, nullptr, nullptr, tQVb,
             Mst, 512, 256, sc, 1.f, cst, snt);
        flash_kernel<<<dim3(16, 2, 16), 256, 0, stream>>>(tQVb, tQVb + 256, Opb, mpb, lpb, 0);
        gemm_oproj<<<dim3(4, 64), 256, 0, stream>>>(Opb, mpb, lpb, wso + oDD, sbo + i * ND, mb);
        gemm(xb, mb, wsw1 + oW1, sb1 + i * 512, nullptr, nullptr, hb,
             Mst, 512, 512, 1.f, 1.f, nullptr, nullptr);
        ln_gelu_wave<<<Mst / 4, 256, 0, stream>>>(hb, sg + i * 512, sbe + i * 512, hgb);
        gemm(hgb, nullptr, wsw2 + oW2, sb2 + i * ND, x, x, xb,
             Mst, 256, 512, 1.f, 1.f, nullptr, nullptr);

        // ---- cross ----
        gemm(xb, nullptr, wcqv + oQV, bqvc + i * 512, nullptr, nullptr, tQVb,
             Mst, 512, 256, sc, 1.f, nullptr, nullptr);
        flash_kernel<<<dim3(16, 2, 16), 256, 0, stream>>>(tQVb, tQVb + 256, Opb, mpb, lpb, 1);
        gemm_oproj<<<dim3(4, 64), 256, 0, stream>>>(Opb, mpb, lpb, wco + oDD, cbo + i * ND, mb);
        gemm(xb, mb, wcw1 + oW1, cb1 + i * 512, nullptr, nullptr, hb,
             Mst, 512, 512, 1.f, 1.f, nullptr, nullptr);
        ln_gelu_wave<<<Mst / 4, 256, 0, stream>>>(hb, cg + i * 512, cbe + i * 512, hgb);
        gemm(hgb, nullptr, wcw2 + oW2, cb2 + i * ND, x, x, xb,
             Mst, 256, 512, 1.f, 1.f, nullptr, nullptr);
    }

    // ---- match head ----
    gemm(xb, nullptr, wpb, bp, nullptr, nullptr, attnb,
         Mst, 256, 256, 0.25f, 0.25f, nullptr, nullptr);          // md stacked
    zproj_kernel<<<Mst, 256, 0, stream>>>(x, Wm, bm, z);
    for (int b = 0; b < NB; ++b) {
        gemm(attnb + (size_t)b * 1024 * 256, nullptr,
             attnb + (size_t)(2048 + b * 1024) * 256, nullptr, nullptr,
             simb + (size_t)b * NN * NN, nullptr,
             1024, 1024, 256, 1.f, 1.f, nullptr, nullptr);
    }
    rowstats_kernel<<<NB * NN, 256, 0, stream>>>(simb, st0, st1, NN);
    colstats_part<<<dim3(NN / 256, CSCH, NB), 256, 0, stream>>>(simb, pmb, psb);
    colstats_red<<<(NB * NN) / 256, 256, 0, stream>>>(pmb, psb, st2, st3);
    int total = NB * NP * NP;
    assemble_kernel<<<(total + 255) / 256, 256, 0, stream>>>(simb, z, z + 2048, st0, st1,
                                                             st2, st3, (float*)d_out);
}

// Round 7
// 1044.537 us; speedup vs baseline: 1.1538x; 1.0010x over previous
//
#include <hip/hip_runtime.h>
#include <hip/hip_bf16.h>
#include <math.h>

#define NB 2
#define NN 1024
#define ND 256
#define NL 6
#define NP (NN + 1)

typedef unsigned short u16;
typedef __attribute__((ext_vector_type(8))) short bf16x8;
typedef __attribute__((ext_vector_type(4))) float f32x4;

__device__ __forceinline__ u16 f2b(float f) {
    union { float f; unsigned u; } v; v.f = f;
    unsigned r = v.u + 0x7FFFu + ((v.u >> 16) & 1u);
    return (u16)(r >> 16);
}
__device__ __forceinline__ float b2f(u16 b) {
    union { unsigned u; float f; } v; v.u = ((unsigned)b) << 16;
    return v.f;
}
__device__ __forceinline__ float logsigf(float x) {
    return (x >= 0.f) ? -log1pf(expf(-x)) : (x - log1pf(expf(x)));
}

// ---------------- RoPE tables ----------------
__global__ void rope_cs_kernel(const float* __restrict__ k0p, const float* __restrict__ k1p,
                               const float* __restrict__ fx, const float* __restrict__ fy,
                               float* __restrict__ cs, float* __restrict__ sn) {
    int idx = blockIdx.x * 256 + threadIdx.x;      // 4096*64
    int row = idx >> 6, j = idx & 63;
    const float* kp = (row < 2048) ? k0p + (size_t)row * 2 : k1p + (size_t)(row - 2048) * 2;
    float kx = kp[0], ky = kp[1];
    float f;
    if (j < 32) f = ((kx - 512.f) * (1.f / 512.f)) * fx[j >> 1];
    else        f = ((ky - 384.f) * (1.f / 512.f)) * fy[(j - 32) >> 1];
    cs[idx] = cosf(f);
    sn[idx] = sinf(f);
}

// ---------------- copy both desc tensors + bf16 mirror ----------------
__global__ void copyconv_kernel(const float* __restrict__ d0, const float* __restrict__ d1,
                                float* __restrict__ outf, u16* __restrict__ outb) {
    int i = blockIdx.x * 256 + threadIdx.x;
    float v = (i < 524288) ? d0[i] : d1[i - 524288];
    outf[i] = v; outb[i] = f2b(v);
}

// ------- multi-weight convert+transpose ----
struct WP6 {
    const float* s[6];
    u16* d[6];
    unsigned long long oz[6];
};
__global__ void wconvM_kernel(WP6 w, int perT, int K, int N) {
    __shared__ float t[32][33];
    int z = blockIdx.z;
    int p = z / perT, l = z - p * perT;
    const float* W = w.s[p] + (size_t)l * K * N;
    u16* Wt = w.d[p] + (size_t)l * w.oz[p];
    int k0 = blockIdx.y * 32, n0 = blockIdx.x * 32;
    int tx = threadIdx.x, ty = threadIdx.y;  // 32 x 8
    for (int i = 0; i < 32; i += 8)
        t[ty + i][tx] = W[(size_t)(k0 + ty + i) * N + n0 + tx];
    __syncthreads();
    for (int i = 0; i < 32; i += 8)
        Wt[(size_t)(n0 + ty + i) * K + k0 + tx] = f2b(t[tx][ty + i]);
}

// ---------------- packed qk|v biases for all 12 blocks ----------------
__global__ void biaspack2_kernel(const float* __restrict__ sbqk, const float* __restrict__ sbv,
                                 const float* __restrict__ cbqk, const float* __restrict__ cbv,
                                 float* __restrict__ out) {
    int idx = blockIdx.x * 256 + threadIdx.x;   // 12*512
    if (idx >= 12 * 512) return;
    int z = idx >> 9, c = idx & 511;
    const float* q = (z < 6) ? sbqk + z * 256 : cbqk + (z - 6) * 256;
    const float* v = (z < 6) ? sbv + z * 256 : cbv + (z - 6) * 256;
    out[idx] = (c < 256) ? q[c] : v[c - 256];
}

// ------- Wf[a][n] = sum_j Wo[a][j]*W1[256+j][n]; store wf_z[n][256+a] (bf16 [512][512]) ----
__global__ __launch_bounds__(256)
void wfuse_kernel(const float* __restrict__ sWo, const float* __restrict__ sW1,
                  const float* __restrict__ cWo, const float* __restrict__ cW1,
                  u16* __restrict__ wfs, u16* __restrict__ wfc) {
    __shared__ u16 As[64 * 72];   // As[n][j]
    __shared__ u16 Bs[64 * 72];   // Bs[a][j]
    int z = blockIdx.z;
    const float* Wo = (z < 6) ? sWo + (size_t)z * 65536 : cWo + (size_t)(z - 6) * 65536;
    const float* W1 = (z < 6) ? sW1 + (size_t)z * 262144 : cW1 + (size_t)(z - 6) * 262144;
    u16* out = (z < 6) ? wfs + (size_t)z * 262144 : wfc + (size_t)(z - 6) * 262144;
    int n0 = blockIdx.y * 64, a0 = blockIdx.x * 64;
    int tid = threadIdx.x, lane = tid & 63, wave = tid >> 6;
    int wm = (wave >> 1) * 32, wn = (wave & 1) * 32;
    int l15 = lane & 15, l4 = lane >> 4;
    f32x4 acc[2][2] = {};
    for (int j0 = 0; j0 < 256; j0 += 64) {
        {   // A: transposed stage, coalesced over n
            int nl = tid & 63, jg = tid >> 6;
#pragma unroll
            for (int q = 0; q < 16; ++q) {
                int j = jg * 16 + q;
                As[nl * 72 + j] = f2b(W1[(size_t)(256 + j0 + j) * 512 + n0 + nl]);
            }
        }
        {   // B: direct stage, coalesced over j
            int jl = tid & 63, ag = tid >> 6;
#pragma unroll
            for (int q = 0; q < 16; ++q) {
                int a = ag * 16 + q;
                Bs[a * 72 + jl] = f2b(Wo[(size_t)(a0 + a) * 256 + j0 + jl]);
            }
        }
        __syncthreads();
#pragma unroll
        for (int ks = 0; ks < 2; ++ks) {
            bf16x8 af0 = *(bf16x8*)&As[(wm + l15) * 72 + ks * 32 + l4 * 8];
            bf16x8 af1 = *(bf16x8*)&As[(wm + 16 + l15) * 72 + ks * 32 + l4 * 8];
            bf16x8 bf0 = *(bf16x8*)&Bs[(wn + l15) * 72 + ks * 32 + l4 * 8];
            bf16x8 bf1 = *(bf16x8*)&Bs[(wn + 16 + l15) * 72 + ks * 32 + l4 * 8];
            acc[0][0] = __builtin_amdgcn_mfma_f32_16x16x32_bf16(af0, bf0, acc[0][0], 0, 0, 0);
            acc[0][1] = __builtin_amdgcn_mfma_f32_16x16x32_bf16(af0, bf1, acc[0][1], 0, 0, 0);
            acc[1][0] = __builtin_amdgcn_mfma_f32_16x16x32_bf16(af1, bf0, acc[1][0], 0, 0, 0);
            acc[1][1] = __builtin_amdgcn_mfma_f32_16x16x32_bf16(af1, bf1, acc[1][1], 0, 0, 0);
        }
        __syncthreads();
    }
#pragma unroll
    for (int mi = 0; mi < 2; ++mi)
#pragma unroll
        for (int ni = 0; ni < 2; ++ni)
#pragma unroll
            for (int j = 0; j < 4; ++j) {
                int r = n0 + wm + mi * 16 + l4 * 4 + j;     // n index
                int c = a0 + wn + ni * 16 + l15;            // a index
                out[(size_t)r * 512 + 256 + c] = f2b(acc[mi][ni][j]);
            }
}

// ------- bf[z][n] = b1[n] + sum_a bo[a] * W1[256+a][n] ----
__global__ void bfuse_kernel(const float* __restrict__ sb1, const float* __restrict__ sbo,
                             const float* __restrict__ sW1, const float* __restrict__ cb1,
                             const float* __restrict__ cbo, const float* __restrict__ cW1,
                             float* __restrict__ bfb) {
    int z = blockIdx.y;
    int n = blockIdx.x * 256 + threadIdx.x;
    const float* b1 = (z < 6) ? sb1 + z * 512 : cb1 + (z - 6) * 512;
    const float* bo = (z < 6) ? sbo + z * 256 : cbo + (z - 6) * 256;
    const float* W1 = (z < 6) ? sW1 + (size_t)z * 262144 : cW1 + (size_t)(z - 6) * 262144;
    float acc = b1[n];
    for (int a = 0; a < 256; ++a) acc += bo[a] * W1[(size_t)(256 + a) * 512 + n];
    bfb[z * 512 + n] = acc;
}

// ======= generic GEMM: BK=64, double-buffered LDS, one barrier/iter =======
__global__ __launch_bounds__(256)
void gemm_mfma(const u16* __restrict__ A, const u16* __restrict__ Bt,
               const float* __restrict__ bias, const float* __restrict__ res,
               float* __restrict__ Cf, u16* __restrict__ Cb,
               int M, int N, int K, float scale_lo, float scale_hi,
               const float* __restrict__ csp, const float* __restrict__ snp) {
    __shared__ u16 As[2][64 * 72];
    __shared__ u16 Bs[2][64 * 72];
    int tid = threadIdx.x;
    int lane = tid & 63, wave = tid >> 6;
    int row0 = blockIdx.y * 64, col0 = blockIdx.x * 64;
    int wm = (wave >> 1) * 32, wn = (wave & 1) * 32;
    int l15 = lane & 15, l4 = lane >> 4;
    f32x4 acc[2][2] = {};
    int srl = tid >> 3, sc8 = (tid & 7) * 8;

    auto loadA = [&](int k0, int it) -> bf16x8 {
        return *(const bf16x8*)&A[(size_t)(row0 + srl + it * 32) * K + k0 + sc8];
    };
    auto loadB = [&](int k0, int it) -> bf16x8 {
        return *(const bf16x8*)&Bt[(size_t)(col0 + srl + it * 32) * K + k0 + sc8];
    };

    bf16x8 rA0 = loadA(0, 0), rA1 = loadA(0, 1);
    bf16x8 rB0 = loadB(0, 0), rB1 = loadB(0, 1);
    *(bf16x8*)&As[0][srl * 72 + sc8] = rA0;
    *(bf16x8*)&As[0][(srl + 32) * 72 + sc8] = rA1;
    *(bf16x8*)&Bs[0][srl * 72 + sc8] = rB0;
    *(bf16x8*)&Bs[0][(srl + 32) * 72 + sc8] = rB1;
    __syncthreads();

    int nt = K >> 6;
    for (int t = 0; t < nt; ++t) {
        int buf = t & 1;
        bool more = (t + 1) < nt;
        if (more) {
            rA0 = loadA((t + 1) * 64, 0); rA1 = loadA((t + 1) * 64, 1);
            rB0 = loadB((t + 1) * 64, 0); rB1 = loadB((t + 1) * 64, 1);
        }
#pragma unroll
        for (int ks = 0; ks < 2; ++ks) {
            bf16x8 a0 = *(bf16x8*)&As[buf][(wm + l15) * 72 + ks * 32 + l4 * 8];
            bf16x8 a1 = *(bf16x8*)&As[buf][(wm + 16 + l15) * 72 + ks * 32 + l4 * 8];
            bf16x8 b0 = *(bf16x8*)&Bs[buf][(wn + l15) * 72 + ks * 32 + l4 * 8];
            bf16x8 b1 = *(bf16x8*)&Bs[buf][(wn + 16 + l15) * 72 + ks * 32 + l4 * 8];
            acc[0][0] = __builtin_amdgcn_mfma_f32_16x16x32_bf16(a0, b0, acc[0][0], 0, 0, 0);
            acc[0][1] = __builtin_amdgcn_mfma_f32_16x16x32_bf16(a0, b1, acc[0][1], 0, 0, 0);
            acc[1][0] = __builtin_amdgcn_mfma_f32_16x16x32_bf16(a1, b0, acc[1][0], 0, 0, 0);
            acc[1][1] = __builtin_amdgcn_mfma_f32_16x16x32_bf16(a1, b1, acc[1][1], 0, 0, 0);
        }
        if (more) {
            int nb = buf ^ 1;
            *(bf16x8*)&As[nb][srl * 72 + sc8] = rA0;
            *(bf16x8*)&As[nb][(srl + 32) * 72 + sc8] = rA1;
            *(bf16x8*)&Bs[nb][srl * 72 + sc8] = rB0;
            *(bf16x8*)&Bs[nb][(srl + 32) * 72 + sc8] = rB1;
        }
        __syncthreads();
    }
#pragma unroll
    for (int mi = 0; mi < 2; ++mi)
#pragma unroll
        for (int ni = 0; ni < 2; ++ni)
#pragma unroll
            for (int j = 0; j < 4; ++j) {
                int r = row0 + wm + mi * 16 + l4 * 4 + j;
                int c = col0 + wn + ni * 16 + l15;
                float v = acc[mi][ni][j] + (bias ? bias[c] : 0.f);
                float pn = __shfl_xor(v, 1);
                if (csp && c < 256) {
                    float cc = csp[(size_t)r * 64 + (c & 63)];
                    float ss = snp[(size_t)r * 64 + (c & 63)];
                    v = (c & 1) ? (v * cc + pn * ss) : (v * cc - pn * ss);
                }
                v *= (c < 256) ? scale_lo : scale_hi;
                if (res) v += res[(size_t)r * N + c];
                if (Cf) Cf[(size_t)r * N + c] = v;
                if (Cb) Cb[(size_t)r * N + c] = f2b(v);
            }
}

// ======= W1 GEMM with fused flash-partial combine: A = [x | Ocomb], Bt = [W1t ; Wf] =======
__global__ __launch_bounds__(256)
void gemm_w1f(const u16* __restrict__ xb, const float* __restrict__ Op,
              const float* __restrict__ mp, const float* __restrict__ lp,
              const u16* __restrict__ Bt, const float* __restrict__ bias,
              u16* __restrict__ hb) {
    __shared__ u16 As[2][64 * 72];
    __shared__ u16 Bs[2][64 * 72];
    const int N = 512, K = 512;
    int tid = threadIdx.x;
    int lane = tid & 63, wave = tid >> 6;
    int row0 = blockIdx.y * 64, col0 = blockIdx.x * 64;
    int wm = (wave >> 1) * 32, wn = (wave & 1) * 32;
    int l15 = lane & 15, l4 = lane >> 4;
    f32x4 acc[2][2] = {};
    int srl = tid >> 3, sc8 = (tid & 7) * 8;

    auto loadA = [&](int k0, int it) -> bf16x8 {
        int rg = row0 + srl + it * 32;
        int kg = k0 + sc8;
        if (kg < 256) return *(const bf16x8*)&xb[(size_t)rg * 256 + kg];
        int kg2 = kg - 256;
        int h = kg2 >> 6, d0 = kg2 & 63;
        int t = rg >> 11, bb = (rg >> 10) & 1, iq = rg & 1023;
        int ri = (t * 8 + bb * 4 + h) * 1024 + iq;
        size_t base0 = (size_t)ri * 64 + d0;
        size_t base1 = base0 + (size_t)16384 * 64;
        f32x4 a0 = *(const f32x4*)&Op[base0];
        f32x4 a1 = *(const f32x4*)&Op[base0 + 4];
        f32x4 c0 = *(const f32x4*)&Op[base1];
        f32x4 c1 = *(const f32x4*)&Op[base1 + 4];
        float m0 = mp[ri], m1 = mp[16384 + ri];
        float l0 = lp[ri], l1 = lp[16384 + ri];
        float mf = fmaxf(m0, m1);
        float e0 = __expf(m0 - mf), e1 = __expf(m1 - mf);
        float inv = 1.f / (l0 * e0 + l1 * e1);
        e0 *= inv; e1 *= inv;
        u16 o[8];
#pragma unroll
        for (int e = 0; e < 4; ++e) {
            o[e] = f2b(a0[e] * e0 + c0[e] * e1);
            o[4 + e] = f2b(a1[e] * e0 + c1[e] * e1);
        }
        return *(bf16x8*)o;
    };
    auto loadB = [&](int k0, int it) -> bf16x8 {
        return *(const bf16x8*)&Bt[(size_t)(col0 + srl + it * 32) * K + k0 + sc8];
    };

    bf16x8 rA0 = loadA(0, 0), rA1 = loadA(0, 1);
    bf16x8 rB0 = loadB(0, 0), rB1 = loadB(0, 1);
    *(bf16x8*)&As[0][srl * 72 + sc8] = rA0;
    *(bf16x8*)&As[0][(srl + 32) * 72 + sc8] = rA1;
    *(bf16x8*)&Bs[0][srl * 72 + sc8] = rB0;
    *(bf16x8*)&Bs[0][(srl + 32) * 72 + sc8] = rB1;
    __syncthreads();

    for (int t = 0; t < 8; ++t) {
        int buf = t & 1;
        bool more = (t + 1) < 8;
        if (more) {
            rA0 = loadA((t + 1) * 64, 0); rA1 = loadA((t + 1) * 64, 1);
            rB0 = loadB((t + 1) * 64, 0); rB1 = loadB((t + 1) * 64, 1);
        }
#pragma unroll
        for (int ks = 0; ks < 2; ++ks) {
            bf16x8 a0 = *(bf16x8*)&As[buf][(wm + l15) * 72 + ks * 32 + l4 * 8];
            bf16x8 a1 = *(bf16x8*)&As[buf][(wm + 16 + l15) * 72 + ks * 32 + l4 * 8];
            bf16x8 b0 = *(bf16x8*)&Bs[buf][(wn + l15) * 72 + ks * 32 + l4 * 8];
            bf16x8 b1 = *(bf16x8*)&Bs[buf][(wn + 16 + l15) * 72 + ks * 32 + l4 * 8];
            acc[0][0] = __builtin_amdgcn_mfma_f32_16x16x32_bf16(a0, b0, acc[0][0], 0, 0, 0);
            acc[0][1] = __builtin_amdgcn_mfma_f32_16x16x32_bf16(a0, b1, acc[0][1], 0, 0, 0);
            acc[1][0] = __builtin_amdgcn_mfma_f32_16x16x32_bf16(a1, b0, acc[1][0], 0, 0, 0);
            acc[1][1] = __builtin_amdgcn_mfma_f32_16x16x32_bf16(a1, b1, acc[1][1], 0, 0, 0);
        }
        if (more) {
            int nb = buf ^ 1;
            *(bf16x8*)&As[nb][srl * 72 + sc8] = rA0;
            *(bf16x8*)&As[nb][(srl + 32) * 72 + sc8] = rA1;
            *(bf16x8*)&Bs[nb][srl * 72 + sc8] = rB0;
            *(bf16x8*)&Bs[nb][(srl + 32) * 72 + sc8] = rB1;
        }
        __syncthreads();
    }
#pragma unroll
    for (int mi = 0; mi < 2; ++mi)
#pragma unroll
        for (int ni = 0; ni < 2; ++ni)
#pragma unroll
            for (int j = 0; j < 4; ++j) {
                int r = row0 + wm + mi * 16 + l4 * 4 + j;
                int c = col0 + wn + ni * 16 + l15;
                hb[(size_t)r * N + c] = f2b(acc[mi][ni][j] + bias[c]);
            }
}

// ======= LN(512)+GELU: one wave per row =======
__global__ __launch_bounds__(256)
void ln_gelu_wave(const u16* __restrict__ hb, const float* __restrict__ g,
                  const float* __restrict__ be, u16* __restrict__ out) {
    int wave = threadIdx.x >> 6, lane = threadIdx.x & 63;
    int row = blockIdx.x * 4 + wave;
    const u16* p = hb + (size_t)row * 512 + lane * 8;
    bf16x8 v = *(const bf16x8*)p;
    float f[8];
    float sum = 0.f, ss = 0.f;
#pragma unroll
    for (int e = 0; e < 8; ++e) {
        f[e] = b2f(((u16*)&v)[e]);
        sum += f[e]; ss += f[e] * f[e];
    }
#pragma unroll
    for (int d = 1; d < 64; d <<= 1) {
        sum += __shfl_xor(sum, d);
        ss  += __shfl_xor(ss, d);
    }
    float mu = sum * (1.f / 512.f);
    float rstd = rsqrtf(ss * (1.f / 512.f) - mu * mu + 1e-5f);
    f32x4 g0 = *(const f32x4*)&g[lane * 8];
    f32x4 g1 = *(const f32x4*)&g[lane * 8 + 4];
    f32x4 b0 = *(const f32x4*)&be[lane * 8];
    f32x4 b1 = *(const f32x4*)&be[lane * 8 + 4];
    u16 o[8];
#pragma unroll
    for (int e = 0; e < 8; ++e) {
        float gg = (e < 4) ? g0[e] : g1[e - 4];
        float bb = (e < 4) ? b0[e] : b1[e - 4];
        float y = (f[e] - mu) * rstd * gg + bb;
        o[e] = f2b(0.5f * y * (1.f + erff(y * 0.70710678118654752f)));
    }
    *(bf16x8*)(out + (size_t)row * 512 + lane * 8) = *(bf16x8*)o;
}

// ======= flash attention, kv-split 2-way =======
#define QSTR 72
#define VDSTR 1032
#define VBUFE (4 * VDSTR)

__global__ __launch_bounds__(256)
void flash_kernel(const u16* __restrict__ Qp, const u16* __restrict__ Vp,
                  float* __restrict__ Op, float* __restrict__ mp, float* __restrict__ lp,
                  int kswap) {
    __shared__ u16 Qs[64 * QSTR];
    __shared__ u16 Ks[2][64 * QSTR];
    __shared__ u16 Vs[2][VBUFE];
    __shared__ u16 Ps[64 * QSTR];
    int y = blockIdx.z;
    int half = blockIdx.y;
    int t = y >> 3, b = (y >> 2) & 1, h = y & 3;
    int qR = t * 2048 + b * 1024;
    int kt = kswap ? (1 - t) : t;
    int kR = kt * 2048 + b * 1024 + half * 512;
    int i0 = blockIdx.x * 64;
    int tid = threadIdx.x, lane = tid & 63, wave = tid >> 6;
    int l15 = lane & 15, l4 = lane >> 4;
    int wm = wave * 16;
    int srl = tid >> 3, sc8 = (tid & 7) * 8;

    const u16* Qbase = Qp + (size_t)(qR + i0) * 512 + h * 64;
    const u16* Kbase = Qp + (size_t)kR * 512 + h * 64;
    const u16* Vbase = Vp + (size_t)kR * 512 + h * 64;

#pragma unroll
    for (int it = 0; it < 2; ++it) {
        int rr = srl + it * 32;
        *(bf16x8*)&Qs[rr * QSTR + sc8] = *(const bf16x8*)&Qbase[(size_t)rr * 512 + sc8];
        *(bf16x8*)&Ks[0][rr * QSTR + sc8] = *(const bf16x8*)&Kbase[(size_t)rr * 512 + sc8];
        bf16x8 v = *(const bf16x8*)&Vbase[(size_t)rr * 512 + sc8];
        *(bf16x8*)&Vs[0][(sc8 >> 4) * VDSTR + rr * 16 + (sc8 & 15)] = v;
    }
    __syncthreads();

    bf16x8 qf[2];
    qf[0] = *(bf16x8*)&Qs[(wm + l15) * QSTR + l4 * 8];
    qf[1] = *(bf16x8*)&Qs[(wm + l15) * QSTR + 32 + l4 * 8];

    float m[4], l[4];
    f32x4 accO[4] = {};
#pragma unroll
    for (int j = 0; j < 4; ++j) { m[j] = -1e30f; l[j] = 0.f; }

    for (int j0 = 0; j0 < 512; j0 += 64) {
        int buf = (j0 >> 6) & 1;
        bool more = (j0 + 64) < 512;
        bf16x8 nK0, nK1, nV0, nV1;
        if (more) {
            nK0 = *(const bf16x8*)&Kbase[(size_t)(j0 + 64 + srl) * 512 + sc8];
            nK1 = *(const bf16x8*)&Kbase[(size_t)(j0 + 96 + srl) * 512 + sc8];
            nV0 = *(const bf16x8*)&Vbase[(size_t)(j0 + 64 + srl) * 512 + sc8];
            nV1 = *(const bf16x8*)&Vbase[(size_t)(j0 + 96 + srl) * 512 + sc8];
        }
        f32x4 accS[4] = {};
#pragma unroll
        for (int ks = 0; ks < 2; ++ks) {
#pragma unroll
            for (int n = 0; n < 4; ++n) {
                bf16x8 bb = *(bf16x8*)&Ks[buf][(n * 16 + l15) * QSTR + ks * 32 + l4 * 8];
                accS[n] = __builtin_amdgcn_mfma_f32_16x16x32_bf16(qf[ks], bb, accS[n], 0, 0, 0);
            }
        }
        float p[4][4];
#pragma unroll
        for (int j = 0; j < 4; ++j) {
            float tm = fmaxf(fmaxf(accS[0][j], accS[1][j]), fmaxf(accS[2][j], accS[3][j]));
#pragma unroll
            for (int d = 1; d < 16; d <<= 1) tm = fmaxf(tm, __shfl_xor(tm, d));
            float mnew = fmaxf(m[j], tm);
            float rr = __expf(m[j] - mnew);
            float ts = 0.f;
#pragma unroll
            for (int n = 0; n < 4; ++n) {
                float pv = __expf(accS[n][j] - mnew);
                p[n][j] = pv; ts += pv;
            }
#pragma unroll
            for (int d = 1; d < 16; d <<= 1) ts += __shfl_xor(ts, d);
            l[j] = l[j] * rr + ts;
            m[j] = mnew;
#pragma unroll
            for (int n = 0; n < 4; ++n) accO[n][j] *= rr;
        }
#pragma unroll
        for (int n = 0; n < 4; ++n) {
            int kv = n * 16 + l15;
            int c = (kv & 32) + (((kv >> 2) & 3) << 3) + (((kv >> 4) & 1) << 2) + (kv & 3);
#pragma unroll
            for (int j = 0; j < 4; ++j)
                Ps[(wm + l4 * 4 + j) * QSTR + c] = f2b(p[n][j]);
        }
#pragma unroll
        for (int ks = 0; ks < 2; ++ks) {
            bf16x8 a = *(bf16x8*)&Ps[(wm + l15) * QSTR + ks * 32 + l4 * 8];
#pragma unroll
            for (int n = 0; n < 4; ++n) {
                unsigned va = (unsigned)(size_t)(&Vs[buf][n * VDSTR]) + ks * 1024 + lane * 8;
                unsigned long long q0, q1;
                asm volatile("ds_read_b64_tr_b16 %0, %2\n\t"
                             "ds_read_b64_tr_b16 %1, %2 offset:512\n\t"
                             "s_waitcnt lgkmcnt(0)"
                             : "=&v"(q0), "=&v"(q1) : "v"(va) : "memory");
                union { unsigned long long q[2]; bf16x8 v; } uu;
                uu.q[0] = q0; uu.q[1] = q1;
                accO[n] = __builtin_amdgcn_mfma_f32_16x16x32_bf16(a, uu.v, accO[n], 0, 0, 0);
            }
        }
        if (more) {
            int nb = buf ^ 1;
            *(bf16x8*)&Ks[nb][srl * QSTR + sc8] = nK0;
            *(bf16x8*)&Ks[nb][(srl + 32) * QSTR + sc8] = nK1;
            *(bf16x8*)&Vs[nb][(sc8 >> 4) * VDSTR + srl * 16 + (sc8 & 15)] = nV0;
            *(bf16x8*)&Vs[nb][(sc8 >> 4) * VDSTR + (srl + 32) * 16 + (sc8 & 15)] = nV1;
        }
        __syncthreads();
    }
    size_t obase = (size_t)(half * 16 + y) * 1024 + i0;
#pragma unroll
    for (int n = 0; n < 4; ++n)
#pragma unroll
        for (int j = 0; j < 4; ++j) {
            int r = wm + l4 * 4 + j;
            Op[(obase + r) * 64 + n * 16 + l15] = accO[n][j];
        }
    if (l15 == 0) {
#pragma unroll
        for (int j = 0; j < 4; ++j) {
            int r = wm + l4 * 4 + j;
            mp[obase + r] = m[j];
            lp[obase + r] = l[j];
        }
    }
}

// ---------------- per-row max & sumexp ----------------
__global__ void rowstats_kernel(const float* __restrict__ S, float* __restrict__ rm,
                                float* __restrict__ rs, int ncols) {
    __shared__ float sb[256];
    int row = blockIdx.x, tid = threadIdx.x;
    const float* p = S + (size_t)row * ncols;
    float m = -1e30f;
    for (int j = tid; j < ncols; j += 256) m = fmaxf(m, p[j]);
    sb[tid] = m; __syncthreads();
    for (int s = 128; s > 0; s >>= 1) { if (tid < s) sb[tid] = fmaxf(sb[tid], sb[tid + s]); __syncthreads(); }
    m = sb[0]; __syncthreads();
    float s = 0;
    for (int j = tid; j < ncols; j += 256) s += __expf(p[j] - m);
    sb[tid] = s; __syncthreads();
    for (int st = 128; st > 0; st >>= 1) { if (tid < st) sb[tid] += sb[tid + st]; __syncthreads(); }
    if (tid == 0) { rm[row] = m; rs[row] = sb[0]; }
}

// ---------------- column stats: partial + reduce ----------------
#define CSCH 8
__global__ void colstats_part(const float* __restrict__ S, float* __restrict__ pm,
                              float* __restrict__ ps) {
    int mat = blockIdx.z;
    int j = blockIdx.x * 256 + threadIdx.x;
    int r0 = blockIdx.y * (NN / CSCH);
    const float* p = S + (size_t)mat * NN * NN + (size_t)r0 * NN + j;
    float m = -1e30f;
    for (int i = 0; i < NN / CSCH; ++i) m = fmaxf(m, p[(size_t)i * NN]);
    float s = 0;
    for (int i = 0; i < NN / CSCH; ++i) s += __expf(p[(size_t)i * NN] - m);
    int o = (mat * CSCH + blockIdx.y) * NN + j;
    pm[o] = m; ps[o] = s;
}
__global__ void colstats_red(const float* __restrict__ pm, const float* __restrict__ ps,
                             float* __restrict__ cm, float* __restrict__ cs) {
    int idx = blockIdx.x * 256 + threadIdx.x;
    int mat = idx >> 10, j = idx & 1023;
    float m = -1e30f;
#pragma unroll
    for (int k = 0; k < CSCH; ++k) m = fmaxf(m, pm[(mat * CSCH + k) * NN + j]);
    float s = 0;
#pragma unroll
    for (int k = 0; k < CSCH; ++k)
        s += ps[(mat * CSCH + k) * NN + j] * __expf(pm[(mat * CSCH + k) * NN + j] - m);
    cm[idx] = m; cs[idx] = s;
}

// ---------------- z = x @ Wm + bm ----------------
__global__ void zproj_kernel(const float* __restrict__ X, const float* __restrict__ Wm,
                             const float* __restrict__ bm, float* __restrict__ z) {
    __shared__ float sb[256];
    int row = blockIdx.x, tid = threadIdx.x;
    float v = X[(size_t)row * 256 + tid] * Wm[tid];
    sb[tid] = v; __syncthreads();
    for (int s = 128; s > 0; s >>= 1) { if (tid < s) sb[tid] += sb[tid + s]; __syncthreads(); }
    if (tid == 0) z[row] = sb[0] + bm[0];
}

// ---------------- final assemble ----------------
__global__ void assemble_kernel(const float* __restrict__ sim2, const float* __restrict__ z0,
                                const float* __restrict__ z1, const float* __restrict__ rm,
                                const float* __restrict__ rs, const float* __restrict__ cm,
                                const float* __restrict__ cs, float* __restrict__ out) {
    int idx = blockIdx.x * 256 + threadIdx.x;
    if (idx >= NB * NP * NP) return;
    int b = idx / (NP * NP);
    int rem = idx - b * NP * NP;
    int i = rem / NP, j = rem - i * NP;
    float v;
    if (i < NN && j < NN) {
        float s = sim2[((size_t)b * NN + i) * NN + j];
        float lr = s - rm[b * NN + i] - logf(rs[b * NN + i]);
        float lc = s - cm[b * NN + j] - logf(cs[b * NN + j]);
        v = lr + lc + logsigf(z0[b * NN + i]) + logsigf(z1[b * NN + j]);
    } else if (i < NN) {
        v = logsigf(-z0[b * NN + i]);
    } else if (j < NN) {
        v = logsigf(-z1[b * NN + j]);
    } else {
        v = 0.f;
    }
    out[idx] = v;
}

extern "C" void kernel_launch(void* const* d_in, const int* in_sizes, int n_in,
                              void* d_out, int out_size, void* d_ws, size_t ws_size,
                              hipStream_t stream) {
    auto in = [&](int i) { return (const float*)d_in[i]; };
    const float* kpts0 = in(0);
    const float* kpts1 = in(1);
    const float* desc0 = in(2);
    const float* desc1 = in(3);
    const float* fx = in(4);
    const float* fy = in(5);
    const float* sWqk = in(6);  const float* sbqk = in(7);
    const float* sWv  = in(8);  const float* sbv  = in(9);
    const float* sWo  = in(10); const float* sbo  = in(11);
    const float* sW1  = in(12); const float* sb1  = in(13);
    const float* sg   = in(14); const float* sbe  = in(15);
    const float* sW2  = in(16); const float* sb2  = in(17);
    const float* cWqk = in(18); const float* cbqk = in(19);
    const float* cWv  = in(20); const float* cbv  = in(21);
    const float* cWo  = in(22); const float* cbo  = in(23);
    const float* cW1  = in(24); const float* cb1  = in(25);
    const float* cg   = in(26); const float* cbe  = in(27);
    const float* cW2  = in(28); const float* cb2  = in(29);
    const float* Wp = in(30); const float* bp = in(31);
    const float* Wm = in(32); const float* bm = in(33);

    const int Mst = 2 * NB * NN;               // 4096 stacked rows
    const size_t SND = (size_t)Mst * ND;

    char* base = (char*)d_ws;
    size_t off = 0;
    auto allocf = [&](size_t n) { float* p = (float*)(base + off); off += ((n * 4 + 255) & ~(size_t)255); return p; };
    auto allocb = [&](size_t n) { u16* p = (u16*)(base + off);   off += ((n * 2 + 255) & ~(size_t)255); return p; };

    float* x    = allocf(SND);
    float* cst  = allocf((size_t)Mst * 64);
    float* snt  = allocf((size_t)Mst * 64);
    float* simb = allocf((size_t)NB * NN * NN);
    float* Opb  = allocf((size_t)2 * 16384 * 64);     // flash partials (2 halves)
    float* mpb  = allocf((size_t)2 * 16384);
    float* lpb  = allocf((size_t)2 * 16384);
    float* z    = allocf(Mst);
    float* st0  = allocf(2048);
    float* st1  = allocf(2048);
    float* st2  = allocf(2048);
    float* st3  = allocf(2048);
    float* pmb  = allocf((size_t)NB * CSCH * NN);
    float* psb  = allocf((size_t)NB * CSCH * NN);
    float* bqv  = allocf((size_t)12 * 512);
    float* bfb  = allocf((size_t)12 * 512);

    u16* xb    = allocb(SND);
    u16* tQVb  = allocb((size_t)Mst * 512);
    u16* attnb = allocb(SND);
    u16* hb    = allocb((size_t)Mst * 512);
    u16* hgb   = allocb((size_t)Mst * 512);
    u16* wsqv = allocb((size_t)NL * 512 * 256);
    u16* wcqv = allocb((size_t)NL * 512 * 256);
    u16* wfs  = allocb((size_t)NL * 512 * 512);   // fused [W1t ; Wo@W1b] self
    u16* wfc  = allocb((size_t)NL * 512 * 512);   // fused cross
    u16* wsw2 = allocb((size_t)NL * 512 * 256);
    u16* wcw2 = allocb((size_t)NL * 512 * 256);
    u16* wpb  = allocb((size_t)256 * 256);

    // ---- weight conversion: 3 wconv launches + wfuse + bfuse ----
    {
        WP6 wa = {};
        wa.s[0] = sWqk; wa.d[0] = wsqv;             wa.oz[0] = 512 * 256;
        wa.s[1] = sWv;  wa.d[1] = wsqv + 256 * 256; wa.oz[1] = 512 * 256;
        wa.s[2] = cWqk; wa.d[2] = wcqv;             wa.oz[2] = 512 * 256;
        wa.s[3] = cWv;  wa.d[3] = wcqv + 256 * 256; wa.oz[3] = 512 * 256;
        wa.s[4] = Wp;   wa.d[4] = wpb;              wa.oz[4] = 256 * 256;
        wconvM_kernel<<<dim3(8, 8, 25), dim3(32, 8), 0, stream>>>(wa, 6, 256, 256);
        // W1 top half (k<256) -> wfs/wfc cols 0..255 (full [512][512] row stride via K=512)
        WP6 wb = {};
        wb.s[0] = sW1; wb.d[0] = wfs; wb.oz[0] = 512 * 512;
        wb.s[1] = cW1; wb.d[1] = wfc; wb.oz[1] = 512 * 512;
        wconvM_kernel<<<dim3(16, 8, 12), dim3(32, 8), 0, stream>>>(wb, 6, 512, 512);
        WP6 wc = {};
        wc.s[0] = sW2; wc.d[0] = wsw2; wc.oz[0] = 512 * 256;
        wc.s[1] = cW2; wc.d[1] = wcw2; wc.oz[1] = 512 * 256;
        wconvM_kernel<<<dim3(8, 16, 12), dim3(32, 8), 0, stream>>>(wc, 6, 512, 256);
    }
    wfuse_kernel<<<dim3(4, 8, 12), 256, 0, stream>>>(sWo, sW1, cWo, cW1, wfs, wfc);
    bfuse_kernel<<<dim3(2, 12), 256, 0, stream>>>(sb1, sbo, sW1, cb1, cbo, cW1, bfb);
    biaspack2_kernel<<<(12 * 512 + 255) / 256, 256, 0, stream>>>(sbqk, sbv, cbqk, cbv, bqv);

    rope_cs_kernel<<<1024, 256, 0, stream>>>(kpts0, kpts1, fx, fy, cst, snt);
    copyconv_kernel<<<4096, 256, 0, stream>>>(desc0, desc1, x, xb);

    auto gemm = [&](const u16* A, const u16* Bt, const float* bias, const float* res,
                    float* Cf, u16* Cb, int M, int N, int K,
                    float slo, float shi, const float* csp, const float* snp) {
        gemm_mfma<<<dim3(N / 64, M / 64), 256, 0, stream>>>(A, Bt, bias, res, Cf, Cb,
                                                            M, N, K, slo, shi, csp, snp);
    };

    const float sc = 0.35355339059327379f;   // DH^-0.25 per side

    for (int i = 0; i < NL; ++i) {
        const size_t oQV = (size_t)i * 512 * 256;
        const size_t oWF = (size_t)i * 512 * 512;
        const size_t oW2 = (size_t)i * 512 * 256;

        // ---- self ----
        gemm(xb, wsqv + oQV, bqv + i * 512, nullptr, nullptr, tQVb,
             Mst, 512, 256, sc, 1.f, cst, snt);
        flash_kernel<<<dim3(16, 2, 16), 256, 0, stream>>>(tQVb, tQVb + 256, Opb, mpb, lpb, 0);
        gemm_w1f<<<dim3(8, 64), 256, 0, stream>>>(xb, Opb, mpb, lpb, wfs + oWF, bfb + i * 512, hb);
        ln_gelu_wave<<<Mst / 4, 256, 0, stream>>>(hb, sg + i * 512, sbe + i * 512, hgb);
        gemm(hgb, wsw2 + oW2, sb2 + i * ND, x, x, xb,
             Mst, 256, 512, 1.f, 1.f, nullptr, nullptr);

        // ---- cross ----
        gemm(xb, wcqv + oQV, bqv + (6 + i) * 512, nullptr, nullptr, tQVb,
             Mst, 512, 256, sc, 1.f, nullptr, nullptr);
        flash_kernel<<<dim3(16, 2, 16), 256, 0, stream>>>(tQVb, tQVb + 256, Opb, mpb, lpb, 1);
        gemm_w1f<<<dim3(8, 64), 256, 0, stream>>>(xb, Opb, mpb, lpb, wfc + oWF, bfb + (6 + i) * 512, hb);
        ln_gelu_wave<<<Mst / 4, 256, 0, stream>>>(hb, cg + i * 512, cbe + i * 512, hgb);
        gemm(hgb, wcw2 + oW2, cb2 + i * ND, x, x, xb,
             Mst, 256, 512, 1.f, 1.f, nullptr, nullptr);
    }

    // ---- match head ----
    gemm(xb, wpb, bp, nullptr, nullptr, attnb,
         Mst, 256, 256, 0.25f, 0.25f, nullptr, nullptr);          // md stacked
    zproj_kernel<<<Mst, 256, 0, stream>>>(x, Wm, bm, z);
    for (int b = 0; b < NB; ++b) {
        gemm(attnb + (size_t)b * 1024 * 256,
             attnb + (size_t)(2048 + b * 1024) * 256, nullptr, nullptr,
             simb + (size_t)b * NN * NN, nullptr,
             1024, 1024, 256, 1.f, 1.f, nullptr, nullptr);
    }
    rowstats_kernel<<<NB * NN, 256, 0, stream>>>(simb, st0, st1, NN);
    colstats_part<<<dim3(NN / 256, CSCH, NB), 256, 0, stream>>>(simb, pmb, psb);
    colstats_red<<<(NB * NN) / 256, 256, 0, stream>>>(pmb, psb, st2, st3);
    int total = NB * NP * NP;
    assemble_kernel<<<(total + 255) / 256, 256, 0, stream>>>(simb, z, z + 2048, st0, st1,
                                                             st2, st3, (float*)d_out);
}